// Round 3
// baseline (732.574 us; speedup 1.0000x reference)
//
#include <hip/hip_runtime.h>
#include <math.h>

#define DD 512
#define NH 8
#define HD 64
#define NLQ 2048
#define NLK 8192

typedef __attribute__((ext_vector_type(8))) short bf16x8;
typedef __attribute__((ext_vector_type(4))) float f32x4;

#define MFMA16(a, b, c) __builtin_amdgcn_mfma_f32_16x16x32_bf16((a), (b), (c), 0, 0, 0)

__device__ __forceinline__ unsigned short f2bf(float x) {
    unsigned u = __builtin_bit_cast(unsigned, x);
    u += 0x7fffu + ((u >> 16) & 1u);
    return (unsigned short)(u >> 16);
}
__device__ __forceinline__ float bf2f(unsigned short h) {
    unsigned u = ((unsigned)h) << 16;
    return __builtin_bit_cast(float, u);
}

// ---------------------------------------------------------------------------
// GEMM: Y[r][o] = sum_c X[r][c] * W[o][c] + b[o]
// MODE 0: f32 Y rows. MODE 1: bf16 hi/lo rows. MODE 2: bf16 hi TRANSPOSED.
// ---------------------------------------------------------------------------
template <int MODE>
__global__ __launch_bounds__(256) void gemm_wt(const float* __restrict__ X,
                                               const float* __restrict__ W,
                                               const float* __restrict__ b,
                                               float* __restrict__ Y,
                                               short* __restrict__ Yhi,
                                               short* __restrict__ Ylo,
                                               int nrows)
{
    __shared__ float Xs[16][132];
    __shared__ float Ws[16][132];
    const int r0 = blockIdx.x * 128;
    const int o0 = blockIdx.y * 128;
    const int t    = threadIdx.x;
    const int tx   = t & 15;
    const int ty   = t >> 4;
    const int scg  = (t & 3) * 4;
    const int srow = t >> 2;

    float acc[8][8];
#pragma unroll
    for (int i = 0; i < 8; ++i)
#pragma unroll
        for (int j = 0; j < 8; ++j) acc[i][j] = 0.f;

    for (int kc = 0; kc < DD; kc += 16) {
        __syncthreads();
#pragma unroll
        for (int p = 0; p < 2; ++p) {
            const int r = srow + p * 64;
            const float4 xv = *(const float4*)&X[(size_t)(r0 + r) * DD + kc + scg];
            Xs[scg + 0][r] = xv.x; Xs[scg + 1][r] = xv.y;
            Xs[scg + 2][r] = xv.z; Xs[scg + 3][r] = xv.w;
            const float4 wv = *(const float4*)&W[(size_t)(o0 + r) * DD + kc + scg];
            Ws[scg + 0][r] = wv.x; Ws[scg + 1][r] = wv.y;
            Ws[scg + 2][r] = wv.z; Ws[scg + 3][r] = wv.w;
        }
        __syncthreads();
#pragma unroll
        for (int c = 0; c < 16; ++c) {
            const float4 x0 = *(const float4*)&Xs[c][ty * 8];
            const float4 x1 = *(const float4*)&Xs[c][ty * 8 + 4];
            const float4 w0 = *(const float4*)&Ws[c][tx * 8];
            const float4 w1 = *(const float4*)&Ws[c][tx * 8 + 4];
            const float xr[8] = {x0.x, x0.y, x0.z, x0.w, x1.x, x1.y, x1.z, x1.w};
            const float wr[8] = {w0.x, w0.y, w0.z, w0.w, w1.x, w1.y, w1.z, w1.w};
#pragma unroll
            for (int i = 0; i < 8; ++i)
#pragma unroll
                for (int j = 0; j < 8; ++j)
                    acc[i][j] = fmaf(xr[i], wr[j], acc[i][j]);
        }
    }

    if (MODE == 0) {
#pragma unroll
        for (int i = 0; i < 8; ++i) {
            const int r = r0 + ty * 8 + i;
#pragma unroll
            for (int j = 0; j < 8; j += 4) {
                const int o = o0 + tx * 8 + j;
                float4 ov;
                ov.x = acc[i][j + 0] + b[o + 0];
                ov.y = acc[i][j + 1] + b[o + 1];
                ov.z = acc[i][j + 2] + b[o + 2];
                ov.w = acc[i][j + 3] + b[o + 3];
                *(float4*)&Y[(size_t)r * DD + o] = ov;
            }
        }
    } else if (MODE == 1) {
#pragma unroll
        for (int i = 0; i < 8; ++i) {
            const int r = r0 + ty * 8 + i;
            bf16x8 hi, lo;
#pragma unroll
            for (int j = 0; j < 8; ++j) {
                const float v = acc[i][j] + b[o0 + tx * 8 + j];
                const unsigned short h = f2bf(v);
                hi[j] = (short)h;
                lo[j] = (short)f2bf(v - bf2f(h));
            }
            *(bf16x8*)&Yhi[(size_t)r * DD + o0 + tx * 8] = hi;
            *(bf16x8*)&Ylo[(size_t)r * DD + o0 + tx * 8] = lo;
        }
    } else {
#pragma unroll
        for (int j = 0; j < 8; ++j) {
            const int o = o0 + tx * 8 + j;
            const float bo = b[o];
            bf16x8 hi;
#pragma unroll
            for (int i = 0; i < 8; ++i)
                hi[i] = (short)f2bf(acc[i][j] + bo);
            *(bf16x8*)&Yhi[(size_t)o * nrows + r0 + ty * 8] = hi;
        }
    }
}

// ---------------------------------------------------------------------------
// MFMA flash attention, split-bf16 QK^T (3-product), PV = (P hi+lo) x V(hi).
// K-SPLIT: grid 1024 = 8 heads x 32 q-tiles x 4 k-chunks (2048 keys each);
// partial (m, l, unnormalized acc) written to workspace; combine kernel merges.
// LDS 40 KB (single-buffered, reg-staged prefetch) -> 4 blocks/CU.
// Block id = h*128 + qt*4 + kc: the 8 heads sharing a bias slice are 128 apart
// == 0 (mod 8) -> same XCD L2.
// ---------------------------------------------------------------------------
#define QT 64
#define KT 64
#define NKC 4
#define CHUNK (NLK / NKC)
#define NT (CHUNK / KT)

__global__ __launch_bounds__(256, 4) void attn_mfma(const short* __restrict__ qhi,
                                                    const short* __restrict__ qlo,
                                                    const short* __restrict__ khi,
                                                    const short* __restrict__ klo,
                                                    const short* __restrict__ vthi,
                                                    const float* __restrict__ bias,
                                                    const int* __restrict__ mask,
                                                    float* __restrict__ macc,
                                                    float2* __restrict__ mlb)
{
    __shared__ __align__(16) short ksh[KT * HD];
    __shared__ __align__(16) short ksl[KT * HD];
    __shared__ __align__(16) short vth[HD * KT];
    __shared__ __align__(16) short psh[QT * KT];
    __shared__ __align__(16) short psl[QT * KT];

    const int kc = blockIdx.x & 3;
    const int q0 = ((blockIdx.x >> 2) & 31) * QT;
    const int h  = blockIdx.x >> 7;
    const int k0 = kc * CHUNK;

    const int t    = threadIdx.x;
    const int wid  = t >> 6;
    const int lane = t & 63;
    const int g  = lane >> 4;
    const int cl = lane & 15;
    const int swc = ((cl & 7) << 3);

    // Q A-fragments, in registers for the whole kernel
    bf16x8 qah[2], qal[2];
    {
        const size_t qr = (size_t)(q0 + wid * 16 + cl) * DD + h * HD;
        qah[0] = *(const bf16x8*)&qhi[qr + 8 * g];
        qah[1] = *(const bf16x8*)&qhi[qr + 32 + 8 * g];
        qal[0] = *(const bf16x8*)&qlo[qr + 8 * g];
        qal[1] = *(const bf16x8*)&qlo[qr + 32 + 8 * g];
    }

    // staging: thread covers rows kr0, kr0+32, cols db0..db0+7
    const int kr0 = t >> 3;
    const int db0 = (t & 7) * 8;
    const int sw0 = ((kr0 & 7) << 3);

    bf16x8 rkh[2], rkl[2], rvh[2];

    auto stage_load = [&](int ktg) {  // ktg = global key base of tile
        rkh[0] = *(const bf16x8*)&khi[(size_t)(ktg + kr0) * DD + h * HD + db0];
        rkh[1] = *(const bf16x8*)&khi[(size_t)(ktg + kr0 + 32) * DD + h * HD + db0];
        rkl[0] = *(const bf16x8*)&klo[(size_t)(ktg + kr0) * DD + h * HD + db0];
        rkl[1] = *(const bf16x8*)&klo[(size_t)(ktg + kr0 + 32) * DD + h * HD + db0];
        rvh[0] = *(const bf16x8*)&vthi[(size_t)(h * HD + kr0) * NLK + ktg + db0];
        rvh[1] = *(const bf16x8*)&vthi[(size_t)(h * HD + kr0 + 32) * NLK + ktg + db0];
    };
    auto stage_write = [&]() {
        const int i0 = kr0 * HD + (db0 ^ sw0);
        const int i1 = (kr0 + 32) * HD + (db0 ^ sw0);
        *(bf16x8*)&ksh[i0] = rkh[0];
        *(bf16x8*)&ksh[i1] = rkh[1];
        *(bf16x8*)&ksl[i0] = rkl[0];
        *(bf16x8*)&ksl[i1] = rkl[1];
        *(bf16x8*)&vth[i0] = rvh[0];
        *(bf16x8*)&vth[i1] = rvh[1];
    };

    f32x4 acco[4];
    float m_[4], l_[4];
#pragma unroll
    for (int n = 0; n < 4; ++n) acco[n] = (f32x4){0.f, 0.f, 0.f, 0.f};
#pragma unroll
    for (int r = 0; r < 4; ++r) { m_[r] = -1e30f; l_[r] = 0.f; }

    stage_load(k0);

    for (int it = 0; it < NT; ++it) {
        const int ktg = k0 + it * KT;
        __syncthreads();          // all waves done reading LDS of prev tile
        stage_write();
        __syncthreads();          // tile ready

        if (it + 1 < NT) stage_load(ktg + KT);  // global->reg, hidden under compute

        // bias + mask for this tile
        float br[4][4];
        int mk[4];
#pragma unroll
        for (int j = 0; j < 4; ++j) mk[j] = mask[ktg + 16 * j + cl];
#pragma unroll
        for (int r = 0; r < 4; ++r) {
            const size_t bro = (size_t)(q0 + wid * 16 + 4 * g + r) * NLK + ktg + cl;
#pragma unroll
            for (int j = 0; j < 4; ++j) br[r][j] = bias[bro + 16 * j];
        }

        // ---- QK^T ----
        f32x4 sc[4];
#pragma unroll
        for (int j = 0; j < 4; ++j) sc[j] = (f32x4){0.f, 0.f, 0.f, 0.f};
#pragma unroll
        for (int j = 0; j < 4; ++j) {
            const int krow = (16 * j + cl) * HD;
#pragma unroll
            for (int s = 0; s < 2; ++s) {
                const int off = krow + ((32 * s + 8 * g) ^ swc);
                const bf16x8 bh = *(const bf16x8*)&ksh[off];
                const bf16x8 bl = *(const bf16x8*)&ksl[off];
                sc[j] = MFMA16(qah[s], bh, sc[j]);
                sc[j] = MFMA16(qah[s], bl, sc[j]);
                sc[j] = MFMA16(qal[s], bh, sc[j]);
            }
        }

        float fm[4];
#pragma unroll
        for (int j = 0; j < 4; ++j) fm[j] = mk[j] ? -10000.f : 0.f;
#pragma unroll
        for (int j = 0; j < 4; ++j)
#pragma unroll
            for (int r = 0; r < 4; ++r)
                sc[j][r] = fmaf(sc[j][r], 0.125f, br[r][j] + fm[j]);

        // ---- online softmax ----
#pragma unroll
        for (int r = 0; r < 4; ++r) {
            float tm = fmaxf(fmaxf(sc[0][r], sc[1][r]), fmaxf(sc[2][r], sc[3][r]));
            tm = fmaxf(tm, __shfl_xor(tm, 1));
            tm = fmaxf(tm, __shfl_xor(tm, 2));
            tm = fmaxf(tm, __shfl_xor(tm, 4));
            tm = fmaxf(tm, __shfl_xor(tm, 8));
            const float mn = fmaxf(m_[r], tm);
            const float al = __expf(m_[r] - mn);
            m_[r] = mn;
            float pv[4];
            float ts = 0.f;
#pragma unroll
            for (int j = 0; j < 4; ++j) {
                pv[j] = __expf(sc[j][r] - mn);
                ts += pv[j];
            }
            ts += __shfl_xor(ts, 1);
            ts += __shfl_xor(ts, 2);
            ts += __shfl_xor(ts, 4);
            ts += __shfl_xor(ts, 8);
            l_[r] = l_[r] * al + ts;
#pragma unroll
            for (int n = 0; n < 4; ++n) acco[n][r] *= al;

            const int qrow = wid * 16 + 4 * g + r;
            const int sw = ((qrow & 7) << 3);
#pragma unroll
            for (int j = 0; j < 4; ++j) {
                const unsigned short hh = f2bf(pv[j]);
                const unsigned short ll = f2bf(pv[j] - bf2f(hh));
                const int idx = qrow * KT + ((16 * j + cl) ^ sw);
                psh[idx] = (short)hh;
                psl[idx] = (short)ll;
            }
        }

        // ---- PV (P wave-private LDS RAW; V hi only) ----
        bf16x8 pah[2], pal[2];
        {
            const int qr = (wid * 16 + cl) * KT;
            pah[0] = *(const bf16x8*)&psh[qr + ((8 * g) ^ swc)];
            pah[1] = *(const bf16x8*)&psh[qr + ((32 + 8 * g) ^ swc)];
            pal[0] = *(const bf16x8*)&psl[qr + ((8 * g) ^ swc)];
            pal[1] = *(const bf16x8*)&psl[qr + ((32 + 8 * g) ^ swc)];
        }
#pragma unroll
        for (int n = 0; n < 4; ++n) {
            const int drow = (16 * n + cl) * KT;
#pragma unroll
            for (int s = 0; s < 2; ++s) {
                const int off = drow + ((32 * s + 8 * g) ^ swc);
                const bf16x8 vh = *(const bf16x8*)&vth[off];
                acco[n] = MFMA16(pah[s], vh, acco[n]);
                acco[n] = MFMA16(pal[s], vh, acco[n]);
            }
        }
    }

    // epilogue: partial (m, l, acc) -> workspace
#pragma unroll
    for (int r = 0; r < 4; ++r) {
        const int q = q0 + wid * 16 + 4 * g + r;
        const size_t base = ((size_t)(kc * NH + h) * NLQ + q) * HD;
#pragma unroll
        for (int n = 0; n < 4; ++n)
            macc[base + 16 * n + cl] = acco[n][r];
        if (cl == 0)
            mlb[(size_t)(kc * NH + h) * NLQ + q] = make_float2(m_[r], l_[r]);
    }
}

// ---------------------------------------------------------------------------
// Combine NKC partials: out = sum_c exp(m_c - M) acc_c / sum_c exp(m_c - M) l_c
// One wave per (h,q) row; lane = d.
// ---------------------------------------------------------------------------
__global__ __launch_bounds__(256) void attn_combine(const float* __restrict__ macc,
                                                    const float2* __restrict__ mlb,
                                                    float* __restrict__ ao)
{
    const int row = blockIdx.x * 4 + (threadIdx.x >> 6);  // h*NLQ + q
    const int d   = threadIdx.x & 63;
    float m[NKC], l[NKC];
#pragma unroll
    for (int c = 0; c < NKC; ++c) {
        const float2 v = mlb[(size_t)c * NH * NLQ + row];
        m[c] = v.x; l[c] = v.y;
    }
    float M = m[0];
#pragma unroll
    for (int c = 1; c < NKC; ++c) M = fmaxf(M, m[c]);
    float w[NKC], L = 0.f;
#pragma unroll
    for (int c = 0; c < NKC; ++c) { w[c] = __expf(m[c] - M); L += l[c] * w[c]; }
    float s = 0.f;
#pragma unroll
    for (int c = 0; c < NKC; ++c)
        s += macc[((size_t)c * NH * NLQ + row) * HD + d] * w[c];
    const int h = row >> 11;        // row / NLQ
    const int q = row & (NLQ - 1);
    ao[(size_t)q * DD + h * HD + d] = s / L;
}

extern "C" void kernel_launch(void* const* d_in, const int* in_sizes, int n_in,
                              void* d_out, int out_size, void* d_ws, size_t ws_size,
                              hipStream_t stream)
{
    (void)in_sizes; (void)n_in; (void)out_size; (void)ws_size;
    const float* Q    = (const float*)d_in[0];
    const float* K    = (const float*)d_in[1];
    const float* V    = (const float*)d_in[2];
    const int*   mask = (const int*)d_in[3];
    const float* bias = (const float*)d_in[4];
    const float* Win  = (const float*)d_in[5];
    const float* bin  = (const float*)d_in[6];
    const float* Wout = (const float*)d_in[7];
    const float* bout = (const float*)d_in[8];
    float* out = (float*)d_out;

    // workspace (~51 MB): qhi|qlo|khi|klo|vthi (bf16) then macc|ml|ao (f32)
    short* qhi_  = (short*)d_ws;
    short* qlo_  = qhi_  + (size_t)NLQ * DD;
    short* khi_  = qlo_  + (size_t)NLQ * DD;
    short* klo_  = khi_  + (size_t)NLK * DD;
    short* vthi_ = klo_  + (size_t)NLK * DD;
    float* macc_ = (float*)(vthi_ + (size_t)NLK * DD);
    float2* ml_  = (float2*)(macc_ + (size_t)NKC * NH * NLQ * HD);
    float* ao_   = (float*)(ml_ + (size_t)NKC * NH * NLQ);

    gemm_wt<1><<<dim3(NLQ / 128, 4), 256, 0, stream>>>(Q, Win,               bin,          nullptr, qhi_,  qlo_,  NLQ);
    gemm_wt<1><<<dim3(NLK / 128, 4), 256, 0, stream>>>(K, Win + DD * DD,     bin + DD,     nullptr, khi_,  klo_,  NLK);
    gemm_wt<2><<<dim3(NLK / 128, 4), 256, 0, stream>>>(V, Win + 2 * DD * DD, bin + 2 * DD, nullptr, vthi_, nullptr, NLK);
    attn_mfma<<<dim3(NH * 32 * NKC), 256, 0, stream>>>(qhi_, qlo_, khi_, klo_, vthi_, bias, mask, macc_, ml_);
    attn_combine<<<dim3(NH * NLQ / 4), 256, 0, stream>>>(macc_, ml_, ao_);
    gemm_wt<0><<<dim3(NLQ / 128, 4), 256, 0, stream>>>(ao_, Wout, bout, out, nullptr, nullptr, NLQ);
}

// Round 4
// 511.426 us; speedup vs baseline: 1.4324x; 1.4324x over previous
//
#include <hip/hip_runtime.h>
#include <math.h>

#define DD 512
#define NH 8
#define HD 64
#define NLQ 2048
#define NLK 8192

typedef __attribute__((ext_vector_type(8))) short bf16x8;
typedef __attribute__((ext_vector_type(4))) short s16x4;
typedef __attribute__((ext_vector_type(4))) float f32x4;

#define MFMA16(a, b, c) __builtin_amdgcn_mfma_f32_16x16x32_bf16((a), (b), (c), 0, 0, 0)

__device__ __forceinline__ unsigned short f2bf(float x) {
    unsigned u = __builtin_bit_cast(unsigned, x);
    u += 0x7fffu + ((u >> 16) & 1u);
    return (unsigned short)(u >> 16);
}
__device__ __forceinline__ float bf2f(unsigned short h) {
    unsigned u = ((unsigned)h) << 16;
    return __builtin_bit_cast(float, u);
}

// ---------------------------------------------------------------------------
// fp32 -> bf16 hi/lo split (grid-stride-free; n always multiple of 4)
// ---------------------------------------------------------------------------
__global__ __launch_bounds__(256) void cvt_hl(const float* __restrict__ x,
                                              short* __restrict__ hi,
                                              short* __restrict__ lo, int n)
{
    const int i = (blockIdx.x * 256 + threadIdx.x) * 4;
    if (i >= n) return;
    const float4 v = *(const float4*)&x[i];
    const float a[4] = {v.x, v.y, v.z, v.w};
    s16x4 h, l;
#pragma unroll
    for (int j = 0; j < 4; ++j) {
        const unsigned short hh = f2bf(a[j]);
        h[j] = (short)hh;
        l[j] = (short)f2bf(a[j] - bf2f(hh));
    }
    *(s16x4*)&hi[i] = h;
    *(s16x4*)&lo[i] = l;
}

// ---------------------------------------------------------------------------
// MFMA GEMM, split-bf16 (3-product): Y[r][o] = sum_c X[r][c] W[o][c] + b[o]
// X,W given as bf16 hi/lo. 128x128 tile, 4 waves (2x2, 64x64 each), K-chunk 32.
// LDS rows padded to 40 shorts (bank-friendly, 16B-aligned rows).
// MODE 0: f32 rows. MODE 1: bf16 hi/lo rows. MODE 2: bf16-hi transposed.
// ---------------------------------------------------------------------------
template <int MODE>
__global__ __launch_bounds__(256) void gemm_bf(const short* __restrict__ Xhi,
                                               const short* __restrict__ Xlo,
                                               const short* __restrict__ Whi,
                                               const short* __restrict__ Wlo,
                                               const float* __restrict__ b,
                                               float* __restrict__ Y,
                                               short* __restrict__ Yhi,
                                               short* __restrict__ Ylo,
                                               int nrows)
{
    __shared__ __align__(16) short XsH[128 * 40];
    __shared__ __align__(16) short XsL[128 * 40];
    __shared__ __align__(16) short WsH[128 * 40];
    __shared__ __align__(16) short WsL[128 * 40];

    const int r0 = blockIdx.x * 128;
    const int o0 = blockIdx.y * 128;
    const int t    = threadIdx.x;
    const int wid  = t >> 6;
    const int lane = t & 63;
    const int g  = lane >> 4;
    const int c  = lane & 15;
    const int wr = wid >> 1;
    const int wc = wid & 1;
    const int srow = t >> 1;          // 0..127
    const int sk   = (t & 1) * 16;    // 0 or 16

    bf16x8 pxh[2], pxl[2], pwh[2], pwl[2];
    auto ld = [&](int kc) {
#pragma unroll
        for (int i = 0; i < 2; ++i) {
            pxh[i] = *(const bf16x8*)&Xhi[(size_t)(r0 + srow) * DD + kc + sk + 8 * i];
            pxl[i] = *(const bf16x8*)&Xlo[(size_t)(r0 + srow) * DD + kc + sk + 8 * i];
            pwh[i] = *(const bf16x8*)&Whi[(size_t)(o0 + srow) * DD + kc + sk + 8 * i];
            pwl[i] = *(const bf16x8*)&Wlo[(size_t)(o0 + srow) * DD + kc + sk + 8 * i];
        }
    };
    auto st = [&]() {
#pragma unroll
        for (int i = 0; i < 2; ++i) {
            *(bf16x8*)&XsH[srow * 40 + sk + 8 * i] = pxh[i];
            *(bf16x8*)&XsL[srow * 40 + sk + 8 * i] = pxl[i];
            *(bf16x8*)&WsH[srow * 40 + sk + 8 * i] = pwh[i];
            *(bf16x8*)&WsL[srow * 40 + sk + 8 * i] = pwl[i];
        }
    };

    f32x4 acc[4][4];
#pragma unroll
    for (int i = 0; i < 4; ++i)
#pragma unroll
        for (int j = 0; j < 4; ++j) acc[i][j] = (f32x4){0.f, 0.f, 0.f, 0.f};

    ld(0);
    for (int kc = 0; kc < DD; kc += 32) {
        __syncthreads();
        st();
        __syncthreads();
        if (kc + 32 < DD) ld(kc + 32);

        bf16x8 ah[4], al[4], bh[4], bl[4];
#pragma unroll
        for (int qg = 0; qg < 4; ++qg) {
            const int adr = (64 * wr + 16 * qg + c) * 40 + 8 * g;
            ah[qg] = *(const bf16x8*)&XsH[adr];
            al[qg] = *(const bf16x8*)&XsL[adr];
        }
#pragma unroll
        for (int og = 0; og < 4; ++og) {
            const int adr = (64 * wc + 16 * og + c) * 40 + 8 * g;
            bh[og] = *(const bf16x8*)&WsH[adr];
            bl[og] = *(const bf16x8*)&WsL[adr];
        }
#pragma unroll
        for (int qg = 0; qg < 4; ++qg)
#pragma unroll
            for (int og = 0; og < 4; ++og) {
                acc[qg][og] = MFMA16(ah[qg], bh[og], acc[qg][og]);
                acc[qg][og] = MFMA16(ah[qg], bl[og], acc[qg][og]);
                acc[qg][og] = MFMA16(al[qg], bh[og], acc[qg][og]);
            }
    }

#pragma unroll
    for (int qg = 0; qg < 4; ++qg)
#pragma unroll
        for (int og = 0; og < 4; ++og) {
            const int col = o0 + 64 * wc + 16 * og + c;
            const float bo = b[col];
#pragma unroll
            for (int r = 0; r < 4; ++r) {
                const int row = r0 + 64 * wr + 16 * qg + 4 * g + r;
                const float v = acc[qg][og][r] + bo;
                if (MODE == 0) {
                    Y[(size_t)row * DD + col] = v;
                } else if (MODE == 1) {
                    const unsigned short hh = f2bf(v);
                    Yhi[(size_t)row * DD + col] = (short)hh;
                    Ylo[(size_t)row * DD + col] = (short)f2bf(v - bf2f(hh));
                } else {
                    Yhi[(size_t)col * nrows + row] = (short)f2bf(v);
                }
            }
        }
}

// ---------------------------------------------------------------------------
// MFMA flash attention. QT=128 (8 waves x 16q, R2-proven wave shape), KT=64,
// NKC=4 k-chunks. Double-buffered K hi/lo + V hi; P hi/lo single (wave-private).
// LDS exactly 80 KB -> 2 blocks/CU (160 KB) when scheduler allows.
// Grid 512, id = qt*32 + kc*8 + h: heads sharing a bias slice consecutive.
// ---------------------------------------------------------------------------
#define QT 128
#define KT 64
#define NKC 4
#define CHUNK (NLK / NKC)
#define NT (CHUNK / KT)

__global__ __launch_bounds__(512, 4) void attn_mfma(const short* __restrict__ qhi,
                                                    const short* __restrict__ qlo,
                                                    const short* __restrict__ khi,
                                                    const short* __restrict__ klo,
                                                    const short* __restrict__ vthi,
                                                    const float* __restrict__ bias,
                                                    const int* __restrict__ mask,
                                                    float* __restrict__ macc,
                                                    float2* __restrict__ mlb)
{
    __shared__ __align__(16) short ksh[2][KT * HD];
    __shared__ __align__(16) short ksl[2][KT * HD];
    __shared__ __align__(16) short vth[2][KT * HD];
    __shared__ __align__(16) short psh[QT * KT];
    __shared__ __align__(16) short psl[QT * KT];

    const int h  = blockIdx.x & 7;
    const int kc = (blockIdx.x >> 3) & 3;
    const int q0 = (blockIdx.x >> 5) * QT;
    const int k0 = kc * CHUNK;

    const int t    = threadIdx.x;
    const int wid  = t >> 6;          // 0..7
    const int lane = t & 63;
    const int g  = lane >> 4;
    const int cl = lane & 15;
    const int swc = ((cl & 7) << 3);

    // Q A-fragments (16 q rows per wave), registers for whole kernel
    bf16x8 qah[2], qal[2];
    {
        const size_t qr = (size_t)(q0 + wid * 16 + cl) * DD + h * HD;
        qah[0] = *(const bf16x8*)&qhi[qr + 8 * g];
        qah[1] = *(const bf16x8*)&qhi[qr + 32 + 8 * g];
        qal[0] = *(const bf16x8*)&qlo[qr + 8 * g];
        qal[1] = *(const bf16x8*)&qlo[qr + 32 + 8 * g];
    }

    // staging: 512 thr, each covers one (row, 8-col) of each 64x64 array
    const int kr0 = t >> 3;           // 0..63
    const int db0 = (t & 7) * 8;      // 0..56
    const int sw0 = ((kr0 & 7) << 3);

    bf16x8 rkh, rkl, rvh;
    auto stage_load = [&](int ktg) {
        rkh = *(const bf16x8*)&khi[(size_t)(ktg + kr0) * DD + h * HD + db0];
        rkl = *(const bf16x8*)&klo[(size_t)(ktg + kr0) * DD + h * HD + db0];
        rvh = *(const bf16x8*)&vthi[(size_t)(h * HD + kr0) * NLK + ktg + db0];
    };
    auto stage_write = [&](int buf) {
        const int i0 = kr0 * HD + (db0 ^ sw0);
        *(bf16x8*)&ksh[buf][i0] = rkh;
        *(bf16x8*)&ksl[buf][i0] = rkl;
        *(bf16x8*)&vth[buf][i0] = rvh;
    };

    f32x4 acco[4];
    float m_[4], l_[4];
#pragma unroll
    for (int n = 0; n < 4; ++n) acco[n] = (f32x4){0.f, 0.f, 0.f, 0.f};
#pragma unroll
    for (int r = 0; r < 4; ++r) { m_[r] = -1e30f; l_[r] = 0.f; }

    stage_load(k0);
    stage_write(0);
    int cur = 0;

    for (int it = 0; it < NT; ++it) {
        const int ktg = k0 + it * KT;
        __syncthreads();

        if (it + 1 < NT) stage_load(ktg + KT);

        float br[4][4];
        int mk[4];
#pragma unroll
        for (int j = 0; j < 4; ++j) mk[j] = mask[ktg + 16 * j + cl];
#pragma unroll
        for (int r = 0; r < 4; ++r) {
            const size_t bro = (size_t)(q0 + wid * 16 + 4 * g + r) * NLK + ktg + cl;
#pragma unroll
            for (int j = 0; j < 4; ++j) br[r][j] = bias[bro + 16 * j];
        }

        // ---- QK^T ----
        f32x4 sc[4];
#pragma unroll
        for (int j = 0; j < 4; ++j) sc[j] = (f32x4){0.f, 0.f, 0.f, 0.f};
#pragma unroll
        for (int j = 0; j < 4; ++j) {
            const int krow = (16 * j + cl) * HD;
#pragma unroll
            for (int s = 0; s < 2; ++s) {
                const int off = krow + ((32 * s + 8 * g) ^ swc);
                const bf16x8 bh = *(const bf16x8*)&ksh[cur][off];
                const bf16x8 bl = *(const bf16x8*)&ksl[cur][off];
                sc[j] = MFMA16(qah[s], bh, sc[j]);
                sc[j] = MFMA16(qah[s], bl, sc[j]);
                sc[j] = MFMA16(qal[s], bh, sc[j]);
            }
        }

        float fm[4];
#pragma unroll
        for (int j = 0; j < 4; ++j) fm[j] = mk[j] ? -10000.f : 0.f;
#pragma unroll
        for (int j = 0; j < 4; ++j)
#pragma unroll
            for (int r = 0; r < 4; ++r)
                sc[j][r] = fmaf(sc[j][r], 0.125f, br[r][j] + fm[j]);

        // ---- online softmax ----
#pragma unroll
        for (int r = 0; r < 4; ++r) {
            float tm = fmaxf(fmaxf(sc[0][r], sc[1][r]), fmaxf(sc[2][r], sc[3][r]));
            tm = fmaxf(tm, __shfl_xor(tm, 1));
            tm = fmaxf(tm, __shfl_xor(tm, 2));
            tm = fmaxf(tm, __shfl_xor(tm, 4));
            tm = fmaxf(tm, __shfl_xor(tm, 8));
            const float mn = fmaxf(m_[r], tm);
            const float al = __expf(m_[r] - mn);
            m_[r] = mn;
            float pv[4];
            float ts = 0.f;
#pragma unroll
            for (int j = 0; j < 4; ++j) {
                pv[j] = __expf(sc[j][r] - mn);
                ts += pv[j];
            }
            ts += __shfl_xor(ts, 1);
            ts += __shfl_xor(ts, 2);
            ts += __shfl_xor(ts, 4);
            ts += __shfl_xor(ts, 8);
            l_[r] = l_[r] * al + ts;
#pragma unroll
            for (int n = 0; n < 4; ++n) acco[n][r] *= al;

            const int qrow = wid * 16 + 4 * g + r;
            const int sw = ((qrow & 7) << 3);
#pragma unroll
            for (int j = 0; j < 4; ++j) {
                const unsigned short hh = f2bf(pv[j]);
                const unsigned short ll = f2bf(pv[j] - bf2f(hh));
                const int idx = qrow * KT + ((16 * j + cl) ^ sw);
                psh[idx] = (short)hh;
                psl[idx] = (short)ll;
            }
        }

        // ---- PV ----
        bf16x8 pah[2], pal[2];
        {
            const int qr = (wid * 16 + cl) * KT;
            pah[0] = *(const bf16x8*)&psh[qr + ((8 * g) ^ swc)];
            pah[1] = *(const bf16x8*)&psh[qr + ((32 + 8 * g) ^ swc)];
            pal[0] = *(const bf16x8*)&psl[qr + ((8 * g) ^ swc)];
            pal[1] = *(const bf16x8*)&psl[qr + ((32 + 8 * g) ^ swc)];
        }
#pragma unroll
        for (int n = 0; n < 4; ++n) {
            const int drow = (16 * n + cl) * KT;
#pragma unroll
            for (int s = 0; s < 2; ++s) {
                const int off = drow + ((32 * s + 8 * g) ^ swc);
                const bf16x8 vh = *(const bf16x8*)&vth[cur][off];
                acco[n] = MFMA16(pah[s], vh, acco[n]);
                acco[n] = MFMA16(pal[s], vh, acco[n]);
            }
        }

        if (it + 1 < NT) stage_write(cur ^ 1);
        cur ^= 1;
    }

    // epilogue: partial (m, l, acc) -> workspace
#pragma unroll
    for (int r = 0; r < 4; ++r) {
        const int q = q0 + wid * 16 + 4 * g + r;
        const size_t base = ((size_t)(kc * NH + h) * NLQ + q) * HD;
#pragma unroll
        for (int n = 0; n < 4; ++n)
            macc[base + 16 * n + cl] = acco[n][r];
        if (cl == 0)
            mlb[(size_t)(kc * NH + h) * NLQ + q] = make_float2(m_[r], l_[r]);
    }
}

// ---------------------------------------------------------------------------
// Combine NKC partials -> ao as bf16 hi/lo (feeds out-proj GEMM directly)
// ---------------------------------------------------------------------------
__global__ __launch_bounds__(256) void attn_combine(const float* __restrict__ macc,
                                                    const float2* __restrict__ mlb,
                                                    short* __restrict__ aohi,
                                                    short* __restrict__ aolo)
{
    const int row = blockIdx.x * 4 + (threadIdx.x >> 6);  // h*NLQ + q
    const int d   = threadIdx.x & 63;
    float m[NKC], l[NKC];
#pragma unroll
    for (int c = 0; c < NKC; ++c) {
        const float2 v = mlb[(size_t)c * NH * NLQ + row];
        m[c] = v.x; l[c] = v.y;
    }
    float M = m[0];
#pragma unroll
    for (int c = 1; c < NKC; ++c) M = fmaxf(M, m[c]);
    float w[NKC], L = 0.f;
#pragma unroll
    for (int c = 0; c < NKC; ++c) { w[c] = __expf(m[c] - M); L += l[c] * w[c]; }
    float s = 0.f;
#pragma unroll
    for (int c = 0; c < NKC; ++c)
        s += macc[((size_t)c * NH * NLQ + row) * HD + d] * w[c];
    const float v = s / L;
    const int hh = row >> 11;
    const int q  = row & (NLQ - 1);
    const size_t o = (size_t)q * DD + hh * HD + d;
    const unsigned short hb = f2bf(v);
    aohi[o] = (short)hb;
    aolo[o] = (short)f2bf(v - bf2f(hb));
}

extern "C" void kernel_launch(void* const* d_in, const int* in_sizes, int n_in,
                              void* d_out, int out_size, void* d_ws, size_t ws_size,
                              hipStream_t stream)
{
    (void)in_sizes; (void)n_in; (void)out_size; (void)ws_size;
    const float* Q    = (const float*)d_in[0];
    const float* K    = (const float*)d_in[1];
    const float* V    = (const float*)d_in[2];
    const int*   mask = (const int*)d_in[3];
    const float* bias = (const float*)d_in[4];
    const float* Win  = (const float*)d_in[5];
    const float* bin  = (const float*)d_in[6];
    const float* Wout = (const float*)d_in[7];
    const float* bout = (const float*)d_in[8];
    float* out = (float*)d_out;

    // ---- workspace layout (~55 MB, phase-reused) ----
    char* base = (char*)d_ws;
    // Region A (persistent): projected q/k hi+lo, v^T hi
    short* qhi_  = (short*)base;                               // 2 MB
    short* qlo_  = qhi_  + (size_t)NLQ * DD;
    short* khi_  = qlo_  + (size_t)NLQ * DD;                   // 8 MB
    short* klo_  = khi_  + (size_t)NLK * DD;
    short* vthi_ = klo_  + (size_t)NLK * DD;                   // 8 MB
    // Region C (persistent): converted weights hi/lo (Win rows then Wout)
    short* whi_  = vthi_ + (size_t)NLK * DD;                   // 2 MB
    short* wlo_  = whi_  + (size_t)(3 * DD * DD + DD * DD);
    // Region B (phase-reused): cvt input buffers, then attn partials + ao
    char*  Bb    = (char*)(wlo_ + (size_t)4 * DD * DD);
    short* bxhi_ = (short*)Bb;                                 // up to 8 MB
    short* bxlo_ = bxhi_ + (size_t)NLK * DD;                   // up to 8 MB
    float* macc_ = (float*)Bb;                                 // 16.8 MB (after cvt phase)
    float2* ml_  = (float2*)(macc_ + (size_t)NKC * NH * NLQ * HD);
    short* aohi_ = (short*)(ml_ + (size_t)NKC * NH * NLQ);     // 2 MB
    short* aolo_ = aohi_ + (size_t)NLQ * DD;

    const int CV = 256 * 4;  // elems per cvt block

    // weights -> bf16 hi/lo
    cvt_hl<<<(3 * DD * DD + CV - 1) / CV, 256, 0, stream>>>(Win,  whi_, wlo_, 3 * DD * DD);
    cvt_hl<<<(DD * DD + CV - 1) / CV, 256, 0, stream>>>(Wout, whi_ + 3 * DD * DD, wlo_ + 3 * DD * DD, DD * DD);

    // K proj
    cvt_hl<<<(NLK * DD + CV - 1) / CV, 256, 0, stream>>>(K, bxhi_, bxlo_, NLK * DD);
    gemm_bf<1><<<dim3(NLK / 128, 4), 256, 0, stream>>>(bxhi_, bxlo_, whi_ + DD * DD, wlo_ + DD * DD,
                                                       bin + DD, nullptr, khi_, klo_, NLK);
    // V proj (transposed bf16-hi output)
    cvt_hl<<<(NLK * DD + CV - 1) / CV, 256, 0, stream>>>(V, bxhi_, bxlo_, NLK * DD);
    gemm_bf<2><<<dim3(NLK / 128, 4), 256, 0, stream>>>(bxhi_, bxlo_, whi_ + 2 * DD * DD, wlo_ + 2 * DD * DD,
                                                       bin + 2 * DD, nullptr, vthi_, nullptr, NLK);
    // Q proj
    cvt_hl<<<(NLQ * DD + CV - 1) / CV, 256, 0, stream>>>(Q, bxhi_, bxlo_, NLQ * DD);
    gemm_bf<1><<<dim3(NLQ / 128, 4), 256, 0, stream>>>(bxhi_, bxlo_, whi_, wlo_,
                                                       bin, nullptr, qhi_, qlo_, NLQ);

    // attention (k-split) + combine
    attn_mfma<<<dim3((NLQ / QT) * NKC * NH), 512, 0, stream>>>(qhi_, qlo_, khi_, klo_, vthi_,
                                                               bias, mask, macc_, ml_);
    attn_combine<<<dim3(NH * NLQ / 4), 256, 0, stream>>>(macc_, ml_, aohi_, aolo_);

    // out proj -> f32 output
    gemm_bf<0><<<dim3(NLQ / 128, 4), 256, 0, stream>>>(aohi_, aolo_, whi_ + 3 * DD * DD, wlo_ + 3 * DD * DD,
                                                       bout, out, nullptr, nullptr, NLQ);
}

// Round 5
// 397.067 us; speedup vs baseline: 1.8450x; 1.2880x over previous
//
#include <hip/hip_runtime.h>
#include <math.h>

#define DD 512
#define NH 8
#define HD 64
#define NLQ 2048
#define NLK 8192

typedef __attribute__((ext_vector_type(8))) short bf16x8;
typedef __attribute__((ext_vector_type(4))) short s16x4;
typedef __attribute__((ext_vector_type(4))) float f32x4;

#define MFMA16(a, b, c) __builtin_amdgcn_mfma_f32_16x16x32_bf16((a), (b), (c), 0, 0, 0)

__device__ __forceinline__ unsigned short f2bf(float x) {
    unsigned u = __builtin_bit_cast(unsigned, x);
    u += 0x7fffu + ((u >> 16) & 1u);
    return (unsigned short)(u >> 16);
}
__device__ __forceinline__ float bf2f(unsigned short h) {
    unsigned u = ((unsigned)h) << 16;
    return __builtin_bit_cast(float, u);
}

// ---------------------------------------------------------------------------
// fp32 -> bf16 hi/lo split
// ---------------------------------------------------------------------------
__global__ __launch_bounds__(256) void cvt_hl(const float* __restrict__ x,
                                              short* __restrict__ hi,
                                              short* __restrict__ lo, int n)
{
    const int i = (blockIdx.x * 256 + threadIdx.x) * 4;
    if (i >= n) return;
    const float4 v = *(const float4*)&x[i];
    const float a[4] = {v.x, v.y, v.z, v.w};
    s16x4 h, l;
#pragma unroll
    for (int j = 0; j < 4; ++j) {
        const unsigned short hh = f2bf(a[j]);
        h[j] = (short)hh;
        l[j] = (short)f2bf(a[j] - bf2f(hh));
    }
    *(s16x4*)&hi[i] = h;
    *(s16x4*)&lo[i] = l;
}

// ---------------------------------------------------------------------------
// MFMA GEMM, split-bf16 (3-product): Y[r][o] = sum_c X[r][c] W[o][c] + b[o]
// MODE 0: f32 rows. MODE 1: bf16 hi/lo rows. MODE 2: bf16-hi transposed.
// MODE 3: bf16-hi rows.
// ---------------------------------------------------------------------------
template <int MODE>
__global__ __launch_bounds__(256) void gemm_bf(const short* __restrict__ Xhi,
                                               const short* __restrict__ Xlo,
                                               const short* __restrict__ Whi,
                                               const short* __restrict__ Wlo,
                                               const float* __restrict__ b,
                                               float* __restrict__ Y,
                                               short* __restrict__ Yhi,
                                               short* __restrict__ Ylo,
                                               int nrows)
{
    __shared__ __align__(16) short XsH[128 * 40];
    __shared__ __align__(16) short XsL[128 * 40];
    __shared__ __align__(16) short WsH[128 * 40];
    __shared__ __align__(16) short WsL[128 * 40];

    const int r0 = blockIdx.x * 128;
    const int o0 = blockIdx.y * 128;
    const int t    = threadIdx.x;
    const int wid  = t >> 6;
    const int lane = t & 63;
    const int g  = lane >> 4;
    const int c  = lane & 15;
    const int wr = wid >> 1;
    const int wc = wid & 1;
    const int srow = t >> 1;
    const int sk   = (t & 1) * 16;

    bf16x8 pxh[2], pxl[2], pwh[2], pwl[2];
    auto ld = [&](int kc) {
#pragma unroll
        for (int i = 0; i < 2; ++i) {
            pxh[i] = *(const bf16x8*)&Xhi[(size_t)(r0 + srow) * DD + kc + sk + 8 * i];
            pxl[i] = *(const bf16x8*)&Xlo[(size_t)(r0 + srow) * DD + kc + sk + 8 * i];
            pwh[i] = *(const bf16x8*)&Whi[(size_t)(o0 + srow) * DD + kc + sk + 8 * i];
            pwl[i] = *(const bf16x8*)&Wlo[(size_t)(o0 + srow) * DD + kc + sk + 8 * i];
        }
    };
    auto st = [&]() {
#pragma unroll
        for (int i = 0; i < 2; ++i) {
            *(bf16x8*)&XsH[srow * 40 + sk + 8 * i] = pxh[i];
            *(bf16x8*)&XsL[srow * 40 + sk + 8 * i] = pxl[i];
            *(bf16x8*)&WsH[srow * 40 + sk + 8 * i] = pwh[i];
            *(bf16x8*)&WsL[srow * 40 + sk + 8 * i] = pwl[i];
        }
    };

    f32x4 acc[4][4];
#pragma unroll
    for (int i = 0; i < 4; ++i)
#pragma unroll
        for (int j = 0; j < 4; ++j) acc[i][j] = (f32x4){0.f, 0.f, 0.f, 0.f};

    ld(0);
    for (int kc = 0; kc < DD; kc += 32) {
        __syncthreads();
        st();
        __syncthreads();
        if (kc + 32 < DD) ld(kc + 32);

        bf16x8 ah[4], al[4], bh[4], bl[4];
#pragma unroll
        for (int qg = 0; qg < 4; ++qg) {
            const int adr = (64 * wr + 16 * qg + c) * 40 + 8 * g;
            ah[qg] = *(const bf16x8*)&XsH[adr];
            al[qg] = *(const bf16x8*)&XsL[adr];
        }
#pragma unroll
        for (int og = 0; og < 4; ++og) {
            const int adr = (64 * wc + 16 * og + c) * 40 + 8 * g;
            bh[og] = *(const bf16x8*)&WsH[adr];
            bl[og] = *(const bf16x8*)&WsL[adr];
        }
#pragma unroll
        for (int qg = 0; qg < 4; ++qg)
#pragma unroll
            for (int og = 0; og < 4; ++og) {
                acc[qg][og] = MFMA16(ah[qg], bh[og], acc[qg][og]);
                acc[qg][og] = MFMA16(ah[qg], bl[og], acc[qg][og]);
                acc[qg][og] = MFMA16(al[qg], bh[og], acc[qg][og]);
            }
    }

#pragma unroll
    for (int qg = 0; qg < 4; ++qg)
#pragma unroll
        for (int og = 0; og < 4; ++og) {
            const int col = o0 + 64 * wc + 16 * og + c;
            const float bo = b[col];
#pragma unroll
            for (int r = 0; r < 4; ++r) {
                const int row = r0 + 64 * wr + 16 * qg + 4 * g + r;
                const float v = acc[qg][og][r] + bo;
                if (MODE == 0) {
                    Y[(size_t)row * DD + col] = v;
                } else if (MODE == 1) {
                    const unsigned short hh = f2bf(v);
                    Yhi[(size_t)row * DD + col] = (short)hh;
                    Ylo[(size_t)row * DD + col] = (short)f2bf(v - bf2f(hh));
                } else if (MODE == 2) {
                    Yhi[(size_t)col * nrows + row] = (short)f2bf(v);
                } else {
                    Yhi[(size_t)row * DD + col] = (short)f2bf(v);
                }
            }
        }
}

// ---------------------------------------------------------------------------
// MFMA flash attention. QT=128 (8 waves x 16q), KT=64. Pure-bf16 QK^T,
// P(hi) x V(hi) PV. Single-buffered LDS (32 KB) -> 3 blocks/CU at 512 thr
// (launch_bounds(512,6)). k-split NKC=6 (ragged 22/22/21/21/21/21 tiles).
// Grid 768, id = h*96 + qt*6 + kc: heads sharing bias 96 apart == same XCD.
// ---------------------------------------------------------------------------
#define QT 128
#define KT 64
#define NKC 6

__global__ __launch_bounds__(512, 6) void attn_mfma(const short* __restrict__ qhi,
                                                    const short* __restrict__ khi,
                                                    const short* __restrict__ vthi,
                                                    const float* __restrict__ bias,
                                                    const int* __restrict__ mask,
                                                    float* __restrict__ macc,
                                                    float2* __restrict__ mlb)
{
    __shared__ __align__(16) short ksh[KT * HD];   // 8 KB
    __shared__ __align__(16) short vth[KT * HD];   // 8 KB
    __shared__ __align__(16) short psh[QT * KT];   // 16 KB

    const int id = blockIdx.x;
    const int h  = id / 96;
    const int rm = id % 96;
    const int qt = rm / 6;
    const int kc = rm % 6;
    const int q0 = qt * QT;
    const int t0 = kc * 21 + (kc < 2 ? kc : 2);    // start k-tile
    const int nt = 21 + (kc < 2 ? 1 : 0);          // tiles this block

    const int t    = threadIdx.x;
    const int wid  = t >> 6;
    const int lane = t & 63;
    const int g  = lane >> 4;
    const int cl = lane & 15;
    const int swc = ((cl & 7) << 3);

    // Q A-fragments (16 q rows per wave)
    bf16x8 qah[2];
    {
        const size_t qr = (size_t)(q0 + wid * 16 + cl) * DD + h * HD;
        qah[0] = *(const bf16x8*)&qhi[qr + 8 * g];
        qah[1] = *(const bf16x8*)&qhi[qr + 32 + 8 * g];
    }

    // staging: 512 thr, each covers one (row, 8-col) of the two 64x64 arrays
    const int kr0 = t >> 3;
    const int db0 = (t & 7) * 8;
    const int sw0 = ((kr0 & 7) << 3);

    bf16x8 rkh, rvh;
    auto stage_load = [&](int ktg) {
        rkh = *(const bf16x8*)&khi[(size_t)(ktg + kr0) * DD + h * HD + db0];
        rvh = *(const bf16x8*)&vthi[(size_t)(h * HD + kr0) * NLK + ktg + db0];
    };
    auto stage_write = [&]() {
        const int i0 = kr0 * HD + (db0 ^ sw0);
        *(bf16x8*)&ksh[i0] = rkh;
        *(bf16x8*)&vth[i0] = rvh;
    };

    f32x4 acco[4];
    float m_[4], l_[4];
#pragma unroll
    for (int n = 0; n < 4; ++n) acco[n] = (f32x4){0.f, 0.f, 0.f, 0.f};
#pragma unroll
    for (int r = 0; r < 4; ++r) { m_[r] = -1e30f; l_[r] = 0.f; }

    stage_load(t0 * KT);

    for (int it = 0; it < nt; ++it) {
        const int ktg = (t0 + it) * KT;
        __syncthreads();          // prev tile's LDS reads done
        stage_write();
        __syncthreads();          // tile visible

        if (it + 1 < nt) stage_load(ktg + KT);

        float br[4][4];
        int mk[4];
#pragma unroll
        for (int j = 0; j < 4; ++j) mk[j] = mask[ktg + 16 * j + cl];
#pragma unroll
        for (int r = 0; r < 4; ++r) {
            const size_t bro = (size_t)(q0 + wid * 16 + 4 * g + r) * NLK + ktg + cl;
#pragma unroll
            for (int j = 0; j < 4; ++j) br[r][j] = bias[bro + 16 * j];
        }

        // ---- QK^T (bf16-hi only) ----
        f32x4 sc[4];
#pragma unroll
        for (int j = 0; j < 4; ++j) sc[j] = (f32x4){0.f, 0.f, 0.f, 0.f};
#pragma unroll
        for (int j = 0; j < 4; ++j) {
            const int krow = (16 * j + cl) * HD;
#pragma unroll
            for (int s = 0; s < 2; ++s) {
                const bf16x8 bh = *(const bf16x8*)&ksh[krow + ((32 * s + 8 * g) ^ swc)];
                sc[j] = MFMA16(qah[s], bh, sc[j]);
            }
        }

        float fm[4];
#pragma unroll
        for (int j = 0; j < 4; ++j) fm[j] = mk[j] ? -10000.f : 0.f;
#pragma unroll
        for (int j = 0; j < 4; ++j)
#pragma unroll
            for (int r = 0; r < 4; ++r)
                sc[j][r] = fmaf(sc[j][r], 0.125f, br[r][j] + fm[j]);

        // ---- online softmax ----
#pragma unroll
        for (int r = 0; r < 4; ++r) {
            float tm = fmaxf(fmaxf(sc[0][r], sc[1][r]), fmaxf(sc[2][r], sc[3][r]));
            tm = fmaxf(tm, __shfl_xor(tm, 1));
            tm = fmaxf(tm, __shfl_xor(tm, 2));
            tm = fmaxf(tm, __shfl_xor(tm, 4));
            tm = fmaxf(tm, __shfl_xor(tm, 8));
            const float mn = fmaxf(m_[r], tm);
            const float al = __expf(m_[r] - mn);
            m_[r] = mn;
            float pv[4];
            float ts = 0.f;
#pragma unroll
            for (int j = 0; j < 4; ++j) {
                pv[j] = __expf(sc[j][r] - mn);
                ts += pv[j];
            }
            ts += __shfl_xor(ts, 1);
            ts += __shfl_xor(ts, 2);
            ts += __shfl_xor(ts, 4);
            ts += __shfl_xor(ts, 8);
            l_[r] = l_[r] * al + ts;
#pragma unroll
            for (int n = 0; n < 4; ++n) acco[n][r] *= al;

            const int qrow = wid * 16 + 4 * g + r;
            const int sw = ((qrow & 7) << 3);
#pragma unroll
            for (int j = 0; j < 4; ++j)
                psh[qrow * KT + ((16 * j + cl) ^ sw)] = (short)f2bf(pv[j]);
        }

        // ---- PV (P hi x V hi; wave-private LDS RAW) ----
        bf16x8 pah[2];
        {
            const int qr = (wid * 16 + cl) * KT;
            pah[0] = *(const bf16x8*)&psh[qr + ((8 * g) ^ swc)];
            pah[1] = *(const bf16x8*)&psh[qr + ((32 + 8 * g) ^ swc)];
        }
#pragma unroll
        for (int n = 0; n < 4; ++n) {
            const int drow = (16 * n + cl) * KT;
#pragma unroll
            for (int s = 0; s < 2; ++s) {
                const bf16x8 vh = *(const bf16x8*)&vth[drow + ((32 * s + 8 * g) ^ swc)];
                acco[n] = MFMA16(pah[s], vh, acco[n]);
            }
        }
    }

    // epilogue: partial (m, l, acc) -> workspace
#pragma unroll
    for (int r = 0; r < 4; ++r) {
        const int q = q0 + wid * 16 + 4 * g + r;
        const size_t base = ((size_t)(kc * NH + h) * NLQ + q) * HD;
#pragma unroll
        for (int n = 0; n < 4; ++n)
            macc[base + 16 * n + cl] = acco[n][r];
        if (cl == 0)
            mlb[(size_t)(kc * NH + h) * NLQ + q] = make_float2(m_[r], l_[r]);
    }
}

// ---------------------------------------------------------------------------
// Combine NKC partials -> ao as bf16 hi/lo (feeds out-proj GEMM)
// ---------------------------------------------------------------------------
__global__ __launch_bounds__(256) void attn_combine(const float* __restrict__ macc,
                                                    const float2* __restrict__ mlb,
                                                    short* __restrict__ aohi,
                                                    short* __restrict__ aolo)
{
    const int row = blockIdx.x * 4 + (threadIdx.x >> 6);  // h*NLQ + q
    const int d   = threadIdx.x & 63;
    float m[NKC], l[NKC];
#pragma unroll
    for (int c = 0; c < NKC; ++c) {
        const float2 v = mlb[(size_t)c * NH * NLQ + row];
        m[c] = v.x; l[c] = v.y;
    }
    float M = m[0];
#pragma unroll
    for (int c = 1; c < NKC; ++c) M = fmaxf(M, m[c]);
    float w[NKC], L = 0.f;
#pragma unroll
    for (int c = 0; c < NKC; ++c) { w[c] = __expf(m[c] - M); L += l[c] * w[c]; }
    float s = 0.f;
#pragma unroll
    for (int c = 0; c < NKC; ++c)
        s += macc[((size_t)c * NH * NLQ + row) * HD + d] * w[c];
    const float v = s / L;
    const int hh = row >> 11;
    const int q  = row & (NLQ - 1);
    const size_t o = (size_t)q * DD + hh * HD + d;
    const unsigned short hb = f2bf(v);
    aohi[o] = (short)hb;
    aolo[o] = (short)f2bf(v - bf2f(hb));
}

extern "C" void kernel_launch(void* const* d_in, const int* in_sizes, int n_in,
                              void* d_out, int out_size, void* d_ws, size_t ws_size,
                              hipStream_t stream)
{
    (void)in_sizes; (void)n_in; (void)out_size; (void)ws_size;
    const float* Q    = (const float*)d_in[0];
    const float* K    = (const float*)d_in[1];
    const float* V    = (const float*)d_in[2];
    const int*   mask = (const int*)d_in[3];
    const float* bias = (const float*)d_in[4];
    const float* Win  = (const float*)d_in[5];
    const float* bin  = (const float*)d_in[6];
    const float* Wout = (const float*)d_in[7];
    const float* bout = (const float*)d_in[8];
    float* out = (float*)d_out;

    // ---- workspace (~51 MB peak, phase-reused) ----
    short* qhi_  = (short*)d_ws;                               // 2 MB
    short* khi_  = qhi_  + (size_t)NLQ * DD;                   // 8 MB
    short* vthi_ = khi_  + (size_t)NLK * DD;                   // 8 MB
    short* whi_  = vthi_ + (size_t)NLK * DD;                   // 2 MB
    short* wlo_  = whi_  + (size_t)4 * DD * DD;                // 2 MB
    char*  Bb    = (char*)(wlo_ + (size_t)4 * DD * DD);
    short* bxhi_ = (short*)Bb;                                 // 8 MB (proj phase)
    short* bxlo_ = bxhi_ + (size_t)NLK * DD;                   // 8 MB (proj phase)
    float* macc_ = (float*)Bb;                                 // 24 MB (attn phase)
    float2* ml_  = (float2*)(macc_ + (size_t)NKC * NH * NLQ * HD);
    short* aohi_ = (short*)(ml_ + (size_t)NKC * NH * NLQ);     // 2 MB
    short* aolo_ = aohi_ + (size_t)NLQ * DD;                   // 2 MB

    const int CV = 256 * 4;

    // weights -> bf16 hi/lo
    cvt_hl<<<(3 * DD * DD + CV - 1) / CV, 256, 0, stream>>>(Win,  whi_, wlo_, 3 * DD * DD);
    cvt_hl<<<(DD * DD + CV - 1) / CV, 256, 0, stream>>>(Wout, whi_ + 3 * DD * DD, wlo_ + 3 * DD * DD, DD * DD);

    // K proj (bf16-hi rows)
    cvt_hl<<<(NLK * DD + CV - 1) / CV, 256, 0, stream>>>(K, bxhi_, bxlo_, NLK * DD);
    gemm_bf<3><<<dim3(NLK / 128, 4), 256, 0, stream>>>(bxhi_, bxlo_, whi_ + DD * DD, wlo_ + DD * DD,
                                                       bin + DD, nullptr, khi_, nullptr, NLK);
    // V proj (bf16-hi transposed)
    cvt_hl<<<(NLK * DD + CV - 1) / CV, 256, 0, stream>>>(V, bxhi_, bxlo_, NLK * DD);
    gemm_bf<2><<<dim3(NLK / 128, 4), 256, 0, stream>>>(bxhi_, bxlo_, whi_ + 2 * DD * DD, wlo_ + 2 * DD * DD,
                                                       bin + 2 * DD, nullptr, vthi_, nullptr, NLK);
    // Q proj (bf16-hi rows)
    cvt_hl<<<(NLQ * DD + CV - 1) / CV, 256, 0, stream>>>(Q, bxhi_, bxlo_, NLQ * DD);
    gemm_bf<3><<<dim3(NLQ / 128, 4), 256, 0, stream>>>(bxhi_, bxlo_, whi_, wlo_,
                                                       bin, nullptr, qhi_, nullptr, NLQ);

    // attention (k-split, ragged NKC=6) + combine
    attn_mfma<<<dim3(NH * 16 * NKC), 512, 0, stream>>>(qhi_, khi_, vthi_, bias, mask, macc_, ml_);
    attn_combine<<<dim3(NH * NLQ / 4), 256, 0, stream>>>(macc_, ml_, aohi_, aolo_);

    // out proj -> f32 output
    gemm_bf<0><<<dim3(NLQ / 128, 4), 256, 0, stream>>>(aohi_, aolo_, whi_ + 3 * DD * DD, wlo_ + 3 * DD * DD,
                                                       bout, out, nullptr, nullptr, NLQ);
}

// Round 6
// 282.380 us; speedup vs baseline: 2.5943x; 1.4061x over previous
//
#include <hip/hip_runtime.h>
#include <math.h>

#define DD 512
#define NH 8
#define HD 64
#define NLQ 2048
#define NLK 8192

typedef __attribute__((ext_vector_type(8))) short bf16x8;
typedef __attribute__((ext_vector_type(8))) unsigned short u16x8;
typedef __attribute__((ext_vector_type(4))) short s16x4;
typedef __attribute__((ext_vector_type(4))) float f32x4;

#define MFMA16(a, b, c) __builtin_amdgcn_mfma_f32_16x16x32_bf16((a), (b), (c), 0, 0, 0)

__device__ __forceinline__ unsigned short f2bf(float x) {
    unsigned u = __builtin_bit_cast(unsigned, x);
    u += 0x7fffu + ((u >> 16) & 1u);
    return (unsigned short)(u >> 16);
}
__device__ __forceinline__ float bf2f(unsigned short h) {
    unsigned u = ((unsigned)h) << 16;
    return __builtin_bit_cast(float, u);
}
__device__ __forceinline__ unsigned short f2h(float x) {
    return __builtin_bit_cast(unsigned short, (_Float16)x);
}
__device__ __forceinline__ float h2f(unsigned short u) {
    return (float)__builtin_bit_cast(_Float16, u);
}

// ---------------------------------------------------------------------------
// fp32 -> bf16 hi/lo split
// ---------------------------------------------------------------------------
__global__ __launch_bounds__(256) void cvt_hl(const float* __restrict__ x,
                                              short* __restrict__ hi,
                                              short* __restrict__ lo, int n)
{
    const int i = (blockIdx.x * 256 + threadIdx.x) * 4;
    if (i >= n) return;
    const float4 v = *(const float4*)&x[i];
    const float a[4] = {v.x, v.y, v.z, v.w};
    s16x4 h, l;
#pragma unroll
    for (int j = 0; j < 4; ++j) {
        const unsigned short hh = f2bf(a[j]);
        h[j] = (short)hh;
        l[j] = (short)f2bf(a[j] - bf2f(hh));
    }
    *(s16x4*)&hi[i] = h;
    *(s16x4*)&lo[i] = l;
}

// ---------------------------------------------------------------------------
// bias + mask -> fp16, MFMA-fragment-packed:
// bh[((Qg*128 + kt) << 10) + cl*64 + g*16 + r*4 + j] = fp16(bias[q][k]-1e4*mask[k])
// with q = Qg*16 + 4g + r, k = kt*64 + 16j + cl.
// ---------------------------------------------------------------------------
__global__ __launch_bounds__(256) void cvt_bias(const float* __restrict__ bias,
                                                const int* __restrict__ mask,
                                                unsigned short* __restrict__ bh)
{
    const size_t o = ((size_t)blockIdx.x * 256 + threadIdx.x) * 8;
    const int tile = (int)(o >> 10);
    const int tin  = (int)(o & 1023);
    const int Qg = tile >> 7;          // NLK/64 = 128 k-tiles per 16-q group
    const int kt = tile & 127;
    const int cl = tin >> 6;
    const int g  = (tin >> 4) & 3;
    const int r0 = (tin >> 2) & 3;     // 0 or 2 (o is a multiple of 8)
    u16x8 out;
#pragma unroll
    for (int i = 0; i < 8; ++i) {
        const int r = r0 + (i >> 2);
        const int j = i & 3;
        const int q = Qg * 16 + 4 * g + r;
        const int k = kt * 64 + 16 * j + cl;
        const float v = bias[(size_t)q * NLK + k] - 10000.f * (float)mask[k];
        out[i] = f2h(v);
    }
    *(u16x8*)&bh[o] = out;
}

// ---------------------------------------------------------------------------
// MFMA GEMM, split-bf16 (3-product): Y[r][o] = sum_c X[r][c] W[o][c] + b[o]
// MODE 0: f32 rows. MODE 1: bf16 hi/lo rows. MODE 2: bf16-hi transposed.
// MODE 3: bf16-hi rows.
// ---------------------------------------------------------------------------
template <int MODE>
__global__ __launch_bounds__(256) void gemm_bf(const short* __restrict__ Xhi,
                                               const short* __restrict__ Xlo,
                                               const short* __restrict__ Whi,
                                               const short* __restrict__ Wlo,
                                               const float* __restrict__ b,
                                               float* __restrict__ Y,
                                               short* __restrict__ Yhi,
                                               short* __restrict__ Ylo,
                                               int nrows)
{
    __shared__ __align__(16) short XsH[128 * 40];
    __shared__ __align__(16) short XsL[128 * 40];
    __shared__ __align__(16) short WsH[128 * 40];
    __shared__ __align__(16) short WsL[128 * 40];

    const int r0 = blockIdx.x * 128;
    const int o0 = blockIdx.y * 128;
    const int t    = threadIdx.x;
    const int wid  = t >> 6;
    const int lane = t & 63;
    const int g  = lane >> 4;
    const int c  = lane & 15;
    const int wr = wid >> 1;
    const int wc = wid & 1;
    const int srow = t >> 1;
    const int sk   = (t & 1) * 16;

    bf16x8 pxh[2], pxl[2], pwh[2], pwl[2];
    auto ld = [&](int kc) {
#pragma unroll
        for (int i = 0; i < 2; ++i) {
            pxh[i] = *(const bf16x8*)&Xhi[(size_t)(r0 + srow) * DD + kc + sk + 8 * i];
            pxl[i] = *(const bf16x8*)&Xlo[(size_t)(r0 + srow) * DD + kc + sk + 8 * i];
            pwh[i] = *(const bf16x8*)&Whi[(size_t)(o0 + srow) * DD + kc + sk + 8 * i];
            pwl[i] = *(const bf16x8*)&Wlo[(size_t)(o0 + srow) * DD + kc + sk + 8 * i];
        }
    };
    auto st = [&]() {
#pragma unroll
        for (int i = 0; i < 2; ++i) {
            *(bf16x8*)&XsH[srow * 40 + sk + 8 * i] = pxh[i];
            *(bf16x8*)&XsL[srow * 40 + sk + 8 * i] = pxl[i];
            *(bf16x8*)&WsH[srow * 40 + sk + 8 * i] = pwh[i];
            *(bf16x8*)&WsL[srow * 40 + sk + 8 * i] = pwl[i];
        }
    };

    f32x4 acc[4][4];
#pragma unroll
    for (int i = 0; i < 4; ++i)
#pragma unroll
        for (int j = 0; j < 4; ++j) acc[i][j] = (f32x4){0.f, 0.f, 0.f, 0.f};

    ld(0);
    for (int kc = 0; kc < DD; kc += 32) {
        __syncthreads();
        st();
        __syncthreads();
        if (kc + 32 < DD) ld(kc + 32);

        bf16x8 ah[4], al[4], bh[4], bl[4];
#pragma unroll
        for (int qg = 0; qg < 4; ++qg) {
            const int adr = (64 * wr + 16 * qg + c) * 40 + 8 * g;
            ah[qg] = *(const bf16x8*)&XsH[adr];
            al[qg] = *(const bf16x8*)&XsL[adr];
        }
#pragma unroll
        for (int og = 0; og < 4; ++og) {
            const int adr = (64 * wc + 16 * og + c) * 40 + 8 * g;
            bh[og] = *(const bf16x8*)&WsH[adr];
            bl[og] = *(const bf16x8*)&WsL[adr];
        }
#pragma unroll
        for (int qg = 0; qg < 4; ++qg)
#pragma unroll
            for (int og = 0; og < 4; ++og) {
                acc[qg][og] = MFMA16(ah[qg], bh[og], acc[qg][og]);
                acc[qg][og] = MFMA16(ah[qg], bl[og], acc[qg][og]);
                acc[qg][og] = MFMA16(al[qg], bh[og], acc[qg][og]);
            }
    }

#pragma unroll
    for (int qg = 0; qg < 4; ++qg)
#pragma unroll
        for (int og = 0; og < 4; ++og) {
            const int col = o0 + 64 * wc + 16 * og + c;
            const float bo = b[col];
#pragma unroll
            for (int r = 0; r < 4; ++r) {
                const int row = r0 + 64 * wr + 16 * qg + 4 * g + r;
                const float v = acc[qg][og][r] + bo;
                if (MODE == 0) {
                    Y[(size_t)row * DD + col] = v;
                } else if (MODE == 1) {
                    const unsigned short hh = f2bf(v);
                    Yhi[(size_t)row * DD + col] = (short)hh;
                    Ylo[(size_t)row * DD + col] = (short)f2bf(v - bf2f(hh));
                } else if (MODE == 2) {
                    Yhi[(size_t)col * nrows + row] = (short)f2bf(v);
                } else {
                    Yhi[(size_t)row * DD + col] = (short)f2bf(v);
                }
            }
        }
}

// ---------------------------------------------------------------------------
// MFMA flash attention. QT=128 (8 waves x 16q), KT=64, NKC=6 ragged k-chunks.
// Pure-bf16 QK^T, P(hi) x V(hi). Double-buffered K/V LDS (48 KB) -> ONE
// __syncthreads per tile; K/V AND bias (fp16 fragment-packed) prefetched one
// full tile ahead -> no exposed global latency in the tile body.
// Grid 768, id = h*96 + qt*6 + kc: heads sharing bias 96 apart == same XCD.
// ---------------------------------------------------------------------------
#define QT 128
#define KT 64
#define NKC 6

__global__ __launch_bounds__(512, 6) void attn_mfma(const short* __restrict__ qhi,
                                                    const short* __restrict__ khi,
                                                    const short* __restrict__ vthi,
                                                    const unsigned short* __restrict__ biash,
                                                    unsigned short* __restrict__ macc,
                                                    float2* __restrict__ mlb)
{
    __shared__ __align__(16) short ksh[2][KT * HD];   // 2 x 8 KB
    __shared__ __align__(16) short vth[2][KT * HD];   // 2 x 8 KB
    __shared__ __align__(16) short psh[QT * KT];      // 16 KB

    const int id = blockIdx.x;
    const int h  = id / 96;
    const int rm = id % 96;
    const int qt = rm / 6;
    const int kc = rm % 6;
    const int q0 = qt * QT;
    const int t0 = kc * 21 + (kc < 2 ? kc : 2);
    const int nt = 21 + (kc < 2 ? 1 : 0);

    const int t    = threadIdx.x;
    const int wid  = t >> 6;
    const int lane = t & 63;
    const int g  = lane >> 4;
    const int cl = lane & 15;
    const int swc = ((cl & 7) << 3);

    // Q A-fragments (16 q rows per wave)
    bf16x8 qah[2];
    {
        const size_t qr = (size_t)(q0 + wid * 16 + cl) * DD + h * HD;
        qah[0] = *(const bf16x8*)&qhi[qr + 8 * g];
        qah[1] = *(const bf16x8*)&qhi[qr + 32 + 8 * g];
    }

    // K/V staging: 512 thr cover the 64x64 tile, 8 shorts each
    const int kr0 = t >> 3;
    const int db0 = (t & 7) * 8;
    const int sw0 = ((kr0 & 7) << 3);
    bf16x8 rkh, rvh;
    auto stage_load = [&](int ktg) {
        rkh = *(const bf16x8*)&khi[(size_t)(ktg + kr0) * DD + h * HD + db0];
        rvh = *(const bf16x8*)&vthi[(size_t)(h * HD + kr0) * NLK + ktg + db0];
    };
    auto stage_write = [&](int p) {
        const int i0 = kr0 * HD + (db0 ^ sw0);
        *(bf16x8*)&ksh[p][i0] = rkh;
        *(bf16x8*)&vth[p][i0] = rvh;
    };

    // bias prefetch (fragment-packed fp16): 2 x 16B per tile per lane
    const size_t brow = (size_t)((q0 >> 4) + wid) * 128;  // 128 k-tiles per Qg
    const int boff = cl * 64 + g * 16;
    u16x8 bp0, bp1;
    auto bias_pf = [&](int ktile) {
        const size_t ba = ((brow + (size_t)ktile) << 10) + boff;
        bp0 = *(const u16x8*)&biash[ba];
        bp1 = *(const u16x8*)&biash[ba + 8];
    };

    f32x4 acco[4];
    float m_[4], l_[4];
#pragma unroll
    for (int n = 0; n < 4; ++n) acco[n] = (f32x4){0.f, 0.f, 0.f, 0.f};
#pragma unroll
    for (int r = 0; r < 4; ++r) { m_[r] = -1e30f; l_[r] = 0.f; }

    stage_load(t0 * KT);
    bias_pf(t0);

    for (int it = 0; it < nt; ++it) {
        const int p = it & 1;
        stage_write(p);           // regs (tile it) -> LDS buf p
        __syncthreads();          // ONE barrier: buf p ready; buf p readers of it-2 done
        if (it + 1 < nt) stage_load((t0 + it + 1) * KT);

        // ---- QK^T (bf16-hi) ----
        f32x4 sc[4];
#pragma unroll
        for (int j = 0; j < 4; ++j) sc[j] = (f32x4){0.f, 0.f, 0.f, 0.f};
#pragma unroll
        for (int j = 0; j < 4; ++j) {
            const int krow = (16 * j + cl) * HD;
#pragma unroll
            for (int s = 0; s < 2; ++s) {
                const bf16x8 bh = *(const bf16x8*)&ksh[p][krow + ((32 * s + 8 * g) ^ swc)];
                sc[j] = MFMA16(qah[s], bh, sc[j]);
            }
        }

        // ---- scale + bias (mask pre-folded into biash) ----
#pragma unroll
        for (int j = 0; j < 4; ++j)
#pragma unroll
            for (int r = 0; r < 4; ++r) {
                const int i = r * 4 + j;
                const unsigned short u =
                    (i < 8) ? (unsigned short)bp0[i] : (unsigned short)bp1[i - 8];
                sc[j][r] = fmaf(sc[j][r], 0.125f, h2f(u));
            }
        if (it + 1 < nt) bias_pf(t0 + it + 1);   // prefetch next tile's bias

        // ---- online softmax ----
#pragma unroll
        for (int r = 0; r < 4; ++r) {
            float tm = fmaxf(fmaxf(sc[0][r], sc[1][r]), fmaxf(sc[2][r], sc[3][r]));
            tm = fmaxf(tm, __shfl_xor(tm, 1));
            tm = fmaxf(tm, __shfl_xor(tm, 2));
            tm = fmaxf(tm, __shfl_xor(tm, 4));
            tm = fmaxf(tm, __shfl_xor(tm, 8));
            const float mn = fmaxf(m_[r], tm);
            const float al = __expf(m_[r] - mn);
            m_[r] = mn;
            float pv[4];
            float ts = 0.f;
#pragma unroll
            for (int j = 0; j < 4; ++j) {
                pv[j] = __expf(sc[j][r] - mn);
                ts += pv[j];
            }
            ts += __shfl_xor(ts, 1);
            ts += __shfl_xor(ts, 2);
            ts += __shfl_xor(ts, 4);
            ts += __shfl_xor(ts, 8);
            l_[r] = l_[r] * al + ts;
#pragma unroll
            for (int n = 0; n < 4; ++n) acco[n][r] *= al;

            const int qrow = wid * 16 + 4 * g + r;
            const int sw = ((qrow & 7) << 3);
#pragma unroll
            for (int j = 0; j < 4; ++j)
                psh[qrow * KT + ((16 * j + cl) ^ sw)] = (short)f2bf(pv[j]);
        }

        // ---- PV (P hi x V hi; wave-private LDS RAW) ----
        bf16x8 pah[2];
        {
            const int qr = (wid * 16 + cl) * KT;
            pah[0] = *(const bf16x8*)&psh[qr + ((8 * g) ^ swc)];
            pah[1] = *(const bf16x8*)&psh[qr + ((32 + 8 * g) ^ swc)];
        }
#pragma unroll
        for (int n = 0; n < 4; ++n) {
            const int drow = (16 * n + cl) * KT;
#pragma unroll
            for (int s = 0; s < 2; ++s) {
                const bf16x8 vh = *(const bf16x8*)&vth[p][drow + ((32 * s + 8 * g) ^ swc)];
                acco[n] = MFMA16(pah[s], vh, acco[n]);
            }
        }
    }

    // epilogue: partial (m, l, acc) -> workspace (acc as fp16)
#pragma unroll
    for (int r = 0; r < 4; ++r) {
        const int q = q0 + wid * 16 + 4 * g + r;
        const size_t base = ((size_t)(kc * NH + h) * NLQ + q) * HD;
#pragma unroll
        for (int n = 0; n < 4; ++n)
            macc[base + 16 * n + cl] = f2h(acco[n][r]);
        if (cl == 0)
            mlb[(size_t)(kc * NH + h) * NLQ + q] = make_float2(m_[r], l_[r]);
    }
}

// ---------------------------------------------------------------------------
// Combine NKC partials -> ao as bf16 hi/lo (feeds out-proj GEMM)
// ---------------------------------------------------------------------------
__global__ __launch_bounds__(256) void attn_combine(const unsigned short* __restrict__ macc,
                                                    const float2* __restrict__ mlb,
                                                    short* __restrict__ aohi,
                                                    short* __restrict__ aolo)
{
    const int row = blockIdx.x * 4 + (threadIdx.x >> 6);  // h*NLQ + q
    const int d   = threadIdx.x & 63;
    float m[NKC], l[NKC];
#pragma unroll
    for (int c = 0; c < NKC; ++c) {
        const float2 v = mlb[(size_t)c * NH * NLQ + row];
        m[c] = v.x; l[c] = v.y;
    }
    float M = m[0];
#pragma unroll
    for (int c = 1; c < NKC; ++c) M = fmaxf(M, m[c]);
    float w[NKC], L = 0.f;
#pragma unroll
    for (int c = 0; c < NKC; ++c) { w[c] = __expf(m[c] - M); L += l[c] * w[c]; }
    float s = 0.f;
#pragma unroll
    for (int c = 0; c < NKC; ++c)
        s += h2f(macc[((size_t)c * NH * NLQ + row) * HD + d]) * w[c];
    const float v = s / L;
    const int hh = row >> 11;
    const int q  = row & (NLQ - 1);
    const size_t o = (size_t)q * DD + hh * HD + d;
    const unsigned short hb = f2bf(v);
    aohi[o] = (short)hb;
    aolo[o] = (short)f2bf(v - bf2f(hb));
}

extern "C" void kernel_launch(void* const* d_in, const int* in_sizes, int n_in,
                              void* d_out, int out_size, void* d_ws, size_t ws_size,
                              hipStream_t stream)
{
    (void)in_sizes; (void)n_in; (void)out_size; (void)ws_size;
    const float* Q    = (const float*)d_in[0];
    const float* K    = (const float*)d_in[1];
    const float* V    = (const float*)d_in[2];
    const int*   mask = (const int*)d_in[3];
    const float* bias = (const float*)d_in[4];
    const float* Win  = (const float*)d_in[5];
    const float* bin  = (const float*)d_in[6];
    const float* Wout = (const float*)d_in[7];
    const float* bout = (const float*)d_in[8];
    float* out = (float*)d_out;

    // ---- workspace (~71 MB peak, phase-reused) ----
    short* qhi_  = (short*)d_ws;                                // 2 MB
    short* khi_  = qhi_  + (size_t)NLQ * DD;                    // 8 MB
    short* vthi_ = khi_  + (size_t)NLK * DD;                    // 8 MB
    short* whi_  = vthi_ + (size_t)NLK * DD;                    // 2 MB
    short* wlo_  = whi_  + (size_t)4 * DD * DD;                 // 2 MB
    char*  Bb    = (char*)(wlo_ + (size_t)4 * DD * DD);
    // proj phase:
    short* bxhi_ = (short*)Bb;                                  // 8 MB
    short* bxlo_ = bxhi_ + (size_t)NLK * DD;                    // 8 MB
    // attn phase (bias cvt runs after projections, overlaps bx buffers):
    unsigned short* biash_ = (unsigned short*)Bb;               // 32 MB
    unsigned short* macc_  = biash_ + (size_t)NLQ * NLK;        // 12 MB (fp16)
    float2* ml_  = (float2*)(macc_ + (size_t)NKC * NH * NLQ * HD);  // 0.75 MB
    short* aohi_ = (short*)(ml_ + (size_t)NKC * NH * NLQ);      // 2 MB
    short* aolo_ = aohi_ + (size_t)NLQ * DD;                    // 2 MB

    const int CV = 256 * 4;

    // weights -> bf16 hi/lo
    cvt_hl<<<(3 * DD * DD + CV - 1) / CV, 256, 0, stream>>>(Win,  whi_, wlo_, 3 * DD * DD);
    cvt_hl<<<(DD * DD + CV - 1) / CV, 256, 0, stream>>>(Wout, whi_ + 3 * DD * DD, wlo_ + 3 * DD * DD, DD * DD);

    // K proj (bf16-hi rows)
    cvt_hl<<<(NLK * DD + CV - 1) / CV, 256, 0, stream>>>(K, bxhi_, bxlo_, NLK * DD);
    gemm_bf<3><<<dim3(NLK / 128, 4), 256, 0, stream>>>(bxhi_, bxlo_, whi_ + DD * DD, wlo_ + DD * DD,
                                                       bin + DD, nullptr, khi_, nullptr, NLK);
    // V proj (bf16-hi transposed)
    cvt_hl<<<(NLK * DD + CV - 1) / CV, 256, 0, stream>>>(V, bxhi_, bxlo_, NLK * DD);
    gemm_bf<2><<<dim3(NLK / 128, 4), 256, 0, stream>>>(bxhi_, bxlo_, whi_ + 2 * DD * DD, wlo_ + 2 * DD * DD,
                                                       bin + 2 * DD, nullptr, vthi_, nullptr, NLK);
    // Q proj (bf16-hi rows)
    cvt_hl<<<(NLQ * DD + CV - 1) / CV, 256, 0, stream>>>(Q, bxhi_, bxlo_, NLQ * DD);
    gemm_bf<3><<<dim3(NLQ / 128, 4), 256, 0, stream>>>(bxhi_, bxlo_, whi_, wlo_,
                                                       bin, nullptr, qhi_, nullptr, NLQ);

    // bias + mask -> fp16 fragment-packed (after projections; overlaps bx)
    cvt_bias<<<dim3((int)(((size_t)NLQ * NLK) / (256 * 8))), 256, 0, stream>>>(bias, mask, biash_);

    // attention (k-split, ragged NKC=6) + combine
    attn_mfma<<<dim3(NH * 16 * NKC), 512, 0, stream>>>(qhi_, khi_, vthi_, biash_, macc_, ml_);
    attn_combine<<<dim3(NH * NLQ / 4), 256, 0, stream>>>(macc_, ml_, aohi_, aolo_);

    // out proj -> f32 output
    gemm_bf<0><<<dim3(NLQ / 128, 4), 256, 0, stream>>>(aohi_, aolo_, whi_ + 3 * DD * DD, wlo_ + 3 * DD * DD,
                                                       bout, out, nullptr, nullptr, NLQ);
}

// Round 7
// 193.777 us; speedup vs baseline: 3.7805x; 1.4572x over previous
//
#include <hip/hip_runtime.h>
#include <math.h>

#define DD 512
#define NH 8
#define HD 64
#define NLQ 2048
#define NLK 8192
#define LOG2E 1.4426950408889634f

typedef __attribute__((ext_vector_type(8))) short bf16x8;
typedef __attribute__((ext_vector_type(8))) unsigned short u16x8;
typedef __attribute__((ext_vector_type(4))) short s16x4;
typedef __attribute__((ext_vector_type(4))) float f32x4;

#define MFMA16(a, b, c) __builtin_amdgcn_mfma_f32_16x16x32_bf16((a), (b), (c), 0, 0, 0)

__device__ __forceinline__ unsigned short f2bf(float x) {
    unsigned u = __builtin_bit_cast(unsigned, x);
    u += 0x7fffu + ((u >> 16) & 1u);
    return (unsigned short)(u >> 16);
}
__device__ __forceinline__ float bf2f(unsigned short h) {
    unsigned u = ((unsigned)h) << 16;
    return __builtin_bit_cast(float, u);
}
__device__ __forceinline__ unsigned short f2h(float x) {
    return __builtin_bit_cast(unsigned short, (_Float16)x);
}
__device__ __forceinline__ float h2f(unsigned short u) {
    return (float)__builtin_bit_cast(_Float16, u);
}
// HW packed f32->bf16 (RNE), lo = a, hi = b
__device__ __forceinline__ int cvtpk(float a, float b) {
    int r;
    asm("v_cvt_pk_bf16_f32 %0, %1, %2" : "=v"(r) : "v"(a), "v"(b));
    return r;
}

// ---------------------------------------------------------------------------
// fp32 -> bf16 hi/lo split (weights only now)
// ---------------------------------------------------------------------------
__global__ __launch_bounds__(256) void cvt_hl(const float* __restrict__ x,
                                              short* __restrict__ hi,
                                              short* __restrict__ lo, int n)
{
    const int i = (blockIdx.x * 256 + threadIdx.x) * 4;
    if (i >= n) return;
    const float4 v = *(const float4*)&x[i];
    const float a[4] = {v.x, v.y, v.z, v.w};
    s16x4 h, l;
#pragma unroll
    for (int j = 0; j < 4; ++j) {
        const unsigned short hh = f2bf(a[j]);
        h[j] = (short)hh;
        l[j] = (short)f2bf(a[j] - bf2f(hh));
    }
    *(s16x4*)&hi[i] = h;
    *(s16x4*)&lo[i] = l;
}

// ---------------------------------------------------------------------------
// bias+mask -> fp16 in log2 units, packed for SWAPPED-QK fragment order:
// addr = ((Qg*128 + kt)<<10) + lane*16 + j*4 + r
// value = (bias[q][k] - 1e4*mask[k]) * log2(e),
//   q = Qg*16 + (lane&15), k = kt*64 + 16j + 4*(lane>>4) + r.
// Thread handles one lane's 16 values.
// ---------------------------------------------------------------------------
__global__ __launch_bounds__(256) void cvt_bias(const float* __restrict__ bias,
                                                const int* __restrict__ mask,
                                                unsigned short* __restrict__ bh)
{
    const int tid  = blockIdx.x * 256 + threadIdx.x;
    const int tile = tid >> 6;          // (Qg*128 + kt)
    const int l    = tid & 63;
    const int q    = (tile >> 7) * 16 + (l & 15);
    const int kb   = (tile & 127) * 64 + 4 * (l >> 4);
    u16x8 o0, o1;
#pragma unroll
    for (int j = 0; j < 4; ++j) {
        const float4 bv = *(const float4*)&bias[(size_t)q * NLK + kb + 16 * j];
        const int4   mv = *(const int4*)&mask[kb + 16 * j];
        const float a[4] = {bv.x, bv.y, bv.z, bv.w};
        const int   m[4] = {mv.x, mv.y, mv.z, mv.w};
#pragma unroll
        for (int r = 0; r < 4; ++r) {
            const float v = (a[r] - 10000.f * (float)m[r]) * LOG2E;
            const int idx = j * 4 + r;
            if (idx < 8) o0[idx] = f2h(v);
            else         o1[idx - 8] = f2h(v);
        }
    }
    const size_t base = ((size_t)tid) * 16;
    *(u16x8*)&bh[base] = o0;
    *(u16x8*)&bh[base + 8] = o1;
}

// ---------------------------------------------------------------------------
// QKV projection GEMM: fp32 X direct (cvt in staging, hi only), W hi/lo,
// 2-MFMA products (Xh*Wh + Xh*Wl). 128x128 tile, 4 waves.
// MODE 3: bf16 rows, scaled. MODE 2: bf16 transposed, scaled.
// ---------------------------------------------------------------------------
template <int MODE>
__global__ __launch_bounds__(256) void gemm_qkv(const float* __restrict__ X,
                                                const short* __restrict__ Whi,
                                                const short* __restrict__ Wlo,
                                                const float* __restrict__ b,
                                                short* __restrict__ Yhi,
                                                float scale, int nrows)
{
    __shared__ __align__(16) short XsH[128 * 40];
    __shared__ __align__(16) short WsH[128 * 40];
    __shared__ __align__(16) short WsL[128 * 40];

    const int r0 = blockIdx.x * 128;
    const int o0 = blockIdx.y * 128;
    const int t    = threadIdx.x;
    const int wid  = t >> 6;
    const int lane = t & 63;
    const int g  = lane >> 4;
    const int c  = lane & 15;
    const int wr = wid >> 1;
    const int wc = wid & 1;
    const int srow = t >> 1;
    const int sk   = (t & 1) * 16;

    float4 xf[4];
    bf16x8 pwh[2], pwl[2];
    auto ld = [&](int kc) {
#pragma unroll
        for (int i = 0; i < 4; ++i)
            xf[i] = *(const float4*)&X[(size_t)(r0 + srow) * DD + kc + sk + 4 * i];
#pragma unroll
        for (int i = 0; i < 2; ++i) {
            pwh[i] = *(const bf16x8*)&Whi[(size_t)(o0 + srow) * DD + kc + sk + 8 * i];
            pwl[i] = *(const bf16x8*)&Wlo[(size_t)(o0 + srow) * DD + kc + sk + 8 * i];
        }
    };
    auto st = [&]() {
#pragma unroll
        for (int i = 0; i < 2; ++i) {
            int4 w;
            w.x = cvtpk(xf[2 * i].x, xf[2 * i].y);
            w.y = cvtpk(xf[2 * i].z, xf[2 * i].w);
            w.z = cvtpk(xf[2 * i + 1].x, xf[2 * i + 1].y);
            w.w = cvtpk(xf[2 * i + 1].z, xf[2 * i + 1].w);
            *(int4*)&XsH[srow * 40 + sk + 8 * i] = w;
            *(bf16x8*)&WsH[srow * 40 + sk + 8 * i] = pwh[i];
            *(bf16x8*)&WsL[srow * 40 + sk + 8 * i] = pwl[i];
        }
    };

    f32x4 acc[4][4];
#pragma unroll
    for (int i = 0; i < 4; ++i)
#pragma unroll
        for (int j = 0; j < 4; ++j) acc[i][j] = (f32x4){0.f, 0.f, 0.f, 0.f};

    ld(0);
    for (int kc = 0; kc < DD; kc += 32) {
        __syncthreads();
        st();
        __syncthreads();
        if (kc + 32 < DD) ld(kc + 32);

        bf16x8 ah[4], bh[4], bl[4];
#pragma unroll
        for (int qg = 0; qg < 4; ++qg)
            ah[qg] = *(const bf16x8*)&XsH[(64 * wr + 16 * qg + c) * 40 + 8 * g];
#pragma unroll
        for (int og = 0; og < 4; ++og) {
            const int adr = (64 * wc + 16 * og + c) * 40 + 8 * g;
            bh[og] = *(const bf16x8*)&WsH[adr];
            bl[og] = *(const bf16x8*)&WsL[adr];
        }
#pragma unroll
        for (int qg = 0; qg < 4; ++qg)
#pragma unroll
            for (int og = 0; og < 4; ++og) {
                acc[qg][og] = MFMA16(ah[qg], bh[og], acc[qg][og]);
                acc[qg][og] = MFMA16(ah[qg], bl[og], acc[qg][og]);
            }
    }

#pragma unroll
    for (int qg = 0; qg < 4; ++qg)
#pragma unroll
        for (int og = 0; og < 4; ++og) {
            const int col = o0 + 64 * wc + 16 * og + c;
            const float bo = b[col];
#pragma unroll
            for (int r = 0; r < 4; ++r) {
                const int row = r0 + 64 * wr + 16 * qg + 4 * g + r;
                const float v = (acc[qg][og][r] + bo) * scale;
                if (MODE == 3) Yhi[(size_t)row * DD + col] = (short)f2bf(v);
                else           Yhi[(size_t)col * nrows + row] = (short)f2bf(v);
            }
        }
}

// ---------------------------------------------------------------------------
// Out-projection GEMM (exact split path): X hi/lo, W hi/lo, 3-MFMA, f32 out.
// ---------------------------------------------------------------------------
__global__ __launch_bounds__(256) void gemm_out(const short* __restrict__ Xhi,
                                                const short* __restrict__ Xlo,
                                                const short* __restrict__ Whi,
                                                const short* __restrict__ Wlo,
                                                const float* __restrict__ b,
                                                float* __restrict__ Y)
{
    __shared__ __align__(16) short XsH[128 * 40];
    __shared__ __align__(16) short XsL[128 * 40];
    __shared__ __align__(16) short WsH[128 * 40];
    __shared__ __align__(16) short WsL[128 * 40];

    const int r0 = blockIdx.x * 128;
    const int o0 = blockIdx.y * 128;
    const int t    = threadIdx.x;
    const int wid  = t >> 6;
    const int lane = t & 63;
    const int g  = lane >> 4;
    const int c  = lane & 15;
    const int wr = wid >> 1;
    const int wc = wid & 1;
    const int srow = t >> 1;
    const int sk   = (t & 1) * 16;

    bf16x8 pxh[2], pxl[2], pwh[2], pwl[2];
    auto ld = [&](int kc) {
#pragma unroll
        for (int i = 0; i < 2; ++i) {
            pxh[i] = *(const bf16x8*)&Xhi[(size_t)(r0 + srow) * DD + kc + sk + 8 * i];
            pxl[i] = *(const bf16x8*)&Xlo[(size_t)(r0 + srow) * DD + kc + sk + 8 * i];
            pwh[i] = *(const bf16x8*)&Whi[(size_t)(o0 + srow) * DD + kc + sk + 8 * i];
            pwl[i] = *(const bf16x8*)&Wlo[(size_t)(o0 + srow) * DD + kc + sk + 8 * i];
        }
    };
    auto st = [&]() {
#pragma unroll
        for (int i = 0; i < 2; ++i) {
            *(bf16x8*)&XsH[srow * 40 + sk + 8 * i] = pxh[i];
            *(bf16x8*)&XsL[srow * 40 + sk + 8 * i] = pxl[i];
            *(bf16x8*)&WsH[srow * 40 + sk + 8 * i] = pwh[i];
            *(bf16x8*)&WsL[srow * 40 + sk + 8 * i] = pwl[i];
        }
    };

    f32x4 acc[4][4];
#pragma unroll
    for (int i = 0; i < 4; ++i)
#pragma unroll
        for (int j = 0; j < 4; ++j) acc[i][j] = (f32x4){0.f, 0.f, 0.f, 0.f};

    ld(0);
    for (int kc = 0; kc < DD; kc += 32) {
        __syncthreads();
        st();
        __syncthreads();
        if (kc + 32 < DD) ld(kc + 32);

        bf16x8 ah[4], al[4], bh[4], bl[4];
#pragma unroll
        for (int qg = 0; qg < 4; ++qg) {
            const int adr = (64 * wr + 16 * qg + c) * 40 + 8 * g;
            ah[qg] = *(const bf16x8*)&XsH[adr];
            al[qg] = *(const bf16x8*)&XsL[adr];
        }
#pragma unroll
        for (int og = 0; og < 4; ++og) {
            const int adr = (64 * wc + 16 * og + c) * 40 + 8 * g;
            bh[og] = *(const bf16x8*)&WsH[adr];
            bl[og] = *(const bf16x8*)&WsL[adr];
        }
#pragma unroll
        for (int qg = 0; qg < 4; ++qg)
#pragma unroll
            for (int og = 0; og < 4; ++og) {
                acc[qg][og] = MFMA16(ah[qg], bh[og], acc[qg][og]);
                acc[qg][og] = MFMA16(ah[qg], bl[og], acc[qg][og]);
                acc[qg][og] = MFMA16(al[qg], bh[og], acc[qg][og]);
            }
    }

#pragma unroll
    for (int qg = 0; qg < 4; ++qg)
#pragma unroll
        for (int og = 0; og < 4; ++og) {
            const int col = o0 + 64 * wc + 16 * og + c;
            const float bo = b[col];
#pragma unroll
            for (int r = 0; r < 4; ++r) {
                const int row = r0 + 64 * wr + 16 * qg + 4 * g + r;
                Y[(size_t)row * DD + col] = acc[qg][og][r] + bo;
            }
        }
}

// ---------------------------------------------------------------------------
// MFMA flash attention, SWAPPED QK^T + in-register softmax.
// QT=128 (8 waves x 16q), KT=64, NKC=8 (1024-key chunks, 16 tiles).
// sc[j][r] = S[k=16j+4g+r][q=cl] via MFMA(Kfrag, Qfrag) -> row softmax is
// lane-local (16 vals) + 2 shfl. P packed with v_cvt_pk_bf16_f32 and
// redistributed to PV A-frags with bpermute (no LDS round trip).
// exp2 space: Q prescaled by 0.125*log2e, bias prescaled by log2e.
// LDS 32 KB double-buffered K/V; one barrier/tile.
// ---------------------------------------------------------------------------
#define QT 128
#define KT 64
#define NKC 8
#define CHUNK (NLK / NKC)
#define NT (CHUNK / KT)

__global__ __launch_bounds__(512, 4) void attn_mfma(const short* __restrict__ qhi,
                                                    const short* __restrict__ khi,
                                                    const short* __restrict__ vthi,
                                                    const unsigned short* __restrict__ biash,
                                                    unsigned short* __restrict__ macc,
                                                    float2* __restrict__ mlb)
{
    __shared__ __align__(16) short ksh[2][KT * HD];   // 2 x 8 KB
    __shared__ __align__(16) short vth[2][KT * HD];   // 2 x 8 KB

    const int id = blockIdx.x;          // h*128 + qt*8 + kc
    const int h  = id >> 7;
    const int qt = (id >> 3) & 15;
    const int kc = id & 7;
    const int q0 = qt * QT;
    const int k0 = kc * CHUNK;

    const int t    = threadIdx.x;
    const int wid  = t >> 6;
    const int lane = t & 63;
    const int g  = lane >> 4;
    const int cl = lane & 15;
    const int swc = ((cl & 7) << 3);

    // Q fragments (B-operand of swapped QK): Q[q=cl][d=8g+..], prescaled
    bf16x8 qah[2];
    {
        const size_t qr = (size_t)(q0 + wid * 16 + cl) * DD + h * HD;
        qah[0] = *(const bf16x8*)&qhi[qr + 8 * g];
        qah[1] = *(const bf16x8*)&qhi[qr + 32 + 8 * g];
    }

    // K/V staging (reg -> XOR-swizzled LDS)
    const int kr0 = t >> 3;
    const int db0 = (t & 7) * 8;
    const int sw0 = ((kr0 & 7) << 3);
    bf16x8 rkh, rvh;
    auto stage_load = [&](int ktg) {
        rkh = *(const bf16x8*)&khi[(size_t)(ktg + kr0) * DD + h * HD + db0];
        rvh = *(const bf16x8*)&vthi[(size_t)(h * HD + kr0) * NLK + ktg + db0];
    };
    auto stage_write = [&](int p) {
        const int i0 = kr0 * HD + (db0 ^ sw0);
        *(bf16x8*)&ksh[p][i0] = rkh;
        *(bf16x8*)&vth[p][i0] = rvh;
    };

    // bias prefetch: lane's 16 fp16 frag values = 2 x 16B
    const size_t btile0 = (size_t)(qt * 8 + wid) * 128;
    const int boff = lane * 16;
    u16x8 bp0, bp1;
    auto bias_pf = [&](int ktile) {
        const size_t ba = ((btile0 + (size_t)ktile) << 10) + boff;
        bp0 = *(const u16x8*)&biash[ba];
        bp1 = *(const u16x8*)&biash[ba + 8];
    };

    f32x4 acco[4];
#pragma unroll
    for (int n = 0; n < 4; ++n) acco[n] = (f32x4){0.f, 0.f, 0.f, 0.f};
    float m_ = -1e30f, l_ = 0.f;

    // redistribution source lanes (fixed per thread)
    const int sA = ((g & 1) << 5) + cl;   // g_src = 2*(g&1)
    const int sB = sA + 16;               // g_src + 1
    const bool hi2 = (g >= 2);

    stage_load(k0);
    bias_pf(kc * NT);

    for (int it = 0; it < NT; ++it) {
        const int p = it & 1;
        stage_write(p);
        __syncthreads();
        if (it + 1 < NT) stage_load(k0 + (it + 1) * KT);

        // ---- swapped QK^T: sc[j][r] = S[k = 16j+4g+r][q = cl] (log2 units) ----
        f32x4 sc[4];
#pragma unroll
        for (int j = 0; j < 4; ++j) sc[j] = (f32x4){0.f, 0.f, 0.f, 0.f};
#pragma unroll
        for (int j = 0; j < 4; ++j) {
            const int krow = (16 * j + cl) * HD;
#pragma unroll
            for (int s = 0; s < 2; ++s) {
                const bf16x8 kf = *(const bf16x8*)&ksh[p][krow + ((32 * s + 8 * g) ^ swc)];
                sc[j] = MFMA16(kf, qah[s], sc[j]);
            }
        }

        // ---- add bias (mask + log2e prefolded) ----
#pragma unroll
        for (int j = 0; j < 4; ++j)
#pragma unroll
            for (int r = 0; r < 4; ++r) {
                const int i = j * 4 + r;
                const unsigned short u =
                    (i < 8) ? (unsigned short)bp0[i] : (unsigned short)bp1[i - 8];
                sc[j][r] += h2f(u);
            }
        if (it + 1 < NT) bias_pf(kc * NT + it + 1);

        // ---- in-register softmax (lane owns row q=cl; 16 vals + cross-g) ----
        float tm = fmaxf(fmaxf(fmaxf(sc[0][0], sc[0][1]), fmaxf(sc[0][2], sc[0][3])),
                         fmaxf(fmaxf(sc[1][0], sc[1][1]), fmaxf(sc[1][2], sc[1][3])));
        tm = fmaxf(tm, fmaxf(fmaxf(fmaxf(sc[2][0], sc[2][1]), fmaxf(sc[2][2], sc[2][3])),
                             fmaxf(fmaxf(sc[3][0], sc[3][1]), fmaxf(sc[3][2], sc[3][3]))));
        tm = fmaxf(tm, __shfl_xor(tm, 16));
        tm = fmaxf(tm, __shfl_xor(tm, 32));
        const float mn = fmaxf(m_, tm);
        const float al = exp2f(m_ - mn);
        const bool resc = __any(mn > m_);
        m_ = mn;
        float ts = 0.f;
#pragma unroll
        for (int j = 0; j < 4; ++j)
#pragma unroll
            for (int r = 0; r < 4; ++r) {
                sc[j][r] = exp2f(sc[j][r] - mn);
                ts += sc[j][r];
            }
        ts += __shfl_xor(ts, 16);
        ts += __shfl_xor(ts, 32);
        l_ = l_ * al + ts;
        if (resc) {
            float alr[4];
#pragma unroll
            for (int r = 0; r < 4; ++r) alr[r] = __shfl(al, 4 * g + r);
#pragma unroll
            for (int n = 0; n < 4; ++n)
#pragma unroll
                for (int r = 0; r < 4; ++r) acco[n][r] *= alr[r];
        }

        // ---- pack P to bf16 pairs: Wp[j][hh] = (p[j][2hh], p[j][2hh+1]) ----
        int Wp[4][2];
#pragma unroll
        for (int j = 0; j < 4; ++j) {
            Wp[j][0] = cvtpk(sc[j][0], sc[j][1]);
            Wp[j][1] = cvtpk(sc[j][2], sc[j][3]);
        }

        // ---- redistribute to PV A-frags: pah[s] = P[q=cl][k=32s+8g .. +7] ----
        bf16x8 pah[2];
#pragma unroll
        for (int s = 0; s < 2; ++s) {
            const int a0 = __shfl(Wp[2 * s][0], sA);
            const int a1 = __shfl(Wp[2 * s][1], sA);
            const int b0 = __shfl(Wp[2 * s + 1][0], sA);
            const int b1 = __shfl(Wp[2 * s + 1][1], sA);
            const int c0 = __shfl(Wp[2 * s][0], sB);
            const int c1 = __shfl(Wp[2 * s][1], sB);
            const int d0 = __shfl(Wp[2 * s + 1][0], sB);
            const int d1 = __shfl(Wp[2 * s + 1][1], sB);
            int4 w;
            w.x = hi2 ? b0 : a0;
            w.y = hi2 ? b1 : a1;
            w.z = hi2 ? d0 : c0;
            w.w = hi2 ? d1 : c1;
            pah[s] = *(bf16x8*)&w;
        }

        // ---- PV ----
#pragma unroll
        for (int n = 0; n < 4; ++n) {
            const int drow = (16 * n + cl) * HD;
#pragma unroll
            for (int s = 0; s < 2; ++s) {
                const bf16x8 vh = *(const bf16x8*)&vth[p][drow + ((32 * s + 8 * g) ^ swc)];
                acco[n] = MFMA16(pah[s], vh, acco[n]);
            }
        }
    }

    // epilogue: acco[n][r] is O[q=q0+wid*16+4g+r][d=16n+cl]; (m,l) per q=cl
#pragma unroll
    for (int r = 0; r < 4; ++r) {
        const int q = q0 + wid * 16 + 4 * g + r;
        const size_t base = ((size_t)(kc * NH + h) * NLQ + q) * HD;
#pragma unroll
        for (int n = 0; n < 4; ++n)
            macc[base + 16 * n + cl] = f2h(acco[n][r]);
    }
    if (g == 0)
        mlb[(size_t)(kc * NH + h) * NLQ + q0 + wid * 16 + cl] = make_float2(m_, l_);
}

// ---------------------------------------------------------------------------
// Combine NKC partials (m in log2 units) -> ao as bf16 hi/lo
// ---------------------------------------------------------------------------
__global__ __launch_bounds__(256) void attn_combine(const unsigned short* __restrict__ macc,
                                                    const float2* __restrict__ mlb,
                                                    short* __restrict__ aohi,
                                                    short* __restrict__ aolo)
{
    const int row = blockIdx.x * 4 + (threadIdx.x >> 6);  // h*NLQ + q
    const int d   = threadIdx.x & 63;
    float m[NKC], l[NKC];
#pragma unroll
    for (int c = 0; c < NKC; ++c) {
        const float2 v = mlb[(size_t)c * NH * NLQ + row];
        m[c] = v.x; l[c] = v.y;
    }
    float M = m[0];
#pragma unroll
    for (int c = 1; c < NKC; ++c) M = fmaxf(M, m[c]);
    float w[NKC], L = 0.f;
#pragma unroll
    for (int c = 0; c < NKC; ++c) { w[c] = exp2f(m[c] - M); L += l[c] * w[c]; }
    float s = 0.f;
#pragma unroll
    for (int c = 0; c < NKC; ++c)
        s += h2f(macc[((size_t)c * NH * NLQ + row) * HD + d]) * w[c];
    const float v = s / L;
    const int hh = row >> 11;
    const int q  = row & (NLQ - 1);
    const size_t o = (size_t)q * DD + hh * HD + d;
    const unsigned short hb = f2bf(v);
    aohi[o] = (short)hb;
    aolo[o] = (short)f2bf(v - bf2f(hb));
}

extern "C" void kernel_launch(void* const* d_in, const int* in_sizes, int n_in,
                              void* d_out, int out_size, void* d_ws, size_t ws_size,
                              hipStream_t stream)
{
    (void)in_sizes; (void)n_in; (void)out_size; (void)ws_size;
    const float* Q    = (const float*)d_in[0];
    const float* K    = (const float*)d_in[1];
    const float* V    = (const float*)d_in[2];
    const int*   mask = (const int*)d_in[3];
    const float* bias = (const float*)d_in[4];
    const float* Win  = (const float*)d_in[5];
    const float* bin  = (const float*)d_in[6];
    const float* Wout = (const float*)d_in[7];
    const float* bout = (const float*)d_in[8];
    float* out = (float*)d_out;

    // ---- workspace (~75 MB flat) ----
    short* qhi_  = (short*)d_ws;                                // 2 MB
    short* khi_  = qhi_  + (size_t)NLQ * DD;                    // 8 MB
    short* vthi_ = khi_  + (size_t)NLK * DD;                    // 8 MB
    short* whi_  = vthi_ + (size_t)NLK * DD;                    // 2 MB
    short* wlo_  = whi_  + (size_t)4 * DD * DD;                 // 2 MB
    unsigned short* biash_ = (unsigned short*)(wlo_ + (size_t)4 * DD * DD); // 32 MB
    unsigned short* macc_  = biash_ + (size_t)NLQ * NLK;        // 16 MB
    float2* ml_  = (float2*)(macc_ + (size_t)NKC * NH * NLQ * HD);  // 1 MB
    short* aohi_ = (short*)(ml_ + (size_t)NKC * NH * NLQ);      // 2 MB
    short* aolo_ = aohi_ + (size_t)NLQ * DD;                    // 2 MB

    const int CV = 256 * 4;
    const float SCQ = 0.125f * LOG2E;

    // weights -> bf16 hi/lo
    cvt_hl<<<(3 * DD * DD + CV - 1) / CV, 256, 0, stream>>>(Win,  whi_, wlo_, 3 * DD * DD);
    cvt_hl<<<(DD * DD + CV - 1) / CV, 256, 0, stream>>>(Wout, whi_ + 3 * DD * DD, wlo_ + 3 * DD * DD, DD * DD);

    // bias + mask -> fp16 fragment-packed (log2 units)
    cvt_bias<<<(int)(((size_t)NLQ * NLK / 16) / 256), 256, 0, stream>>>(bias, mask, biash_);

    // projections (fp32 X direct)
    gemm_qkv<3><<<dim3(NLQ / 128, 4), 256, 0, stream>>>(Q, whi_, wlo_, bin, qhi_, SCQ, NLQ);
    gemm_qkv<3><<<dim3(NLK / 128, 4), 256, 0, stream>>>(K, whi_ + DD * DD, wlo_ + DD * DD,
                                                        bin + DD, khi_, 1.f, NLK);
    gemm_qkv<2><<<dim3(NLK / 128, 4), 256, 0, stream>>>(V, whi_ + 2 * DD * DD, wlo_ + 2 * DD * DD,
                                                        bin + 2 * DD, vthi_, 1.f, NLK);

    // attention (k-split NKC=8) + combine
    attn_mfma<<<dim3(NH * 16 * NKC), 512, 0, stream>>>(qhi_, khi_, vthi_, biash_, macc_, ml_);
    attn_combine<<<dim3(NH * NLQ / 4), 256, 0, stream>>>(macc_, ml_, aohi_, aolo_);

    // out projection (exact split path)
    gemm_out<<<dim3(NLQ / 128, 4), 256, 0, stream>>>(aohi_, aolo_, whi_ + 3 * DD * DD, wlo_ + 3 * DD * DD,
                                                     bout, out);
}